// Round 8
// baseline (303.910 us; speedup 1.0000x reference)
//
#include <hip/hip_runtime.h>
#include <hip/hip_bf16.h>

// Problem constants
#define L  2048
#define D  32
#define DM 1024
#define H  16
#define DH 64
#define FF 4096

typedef unsigned short u16;
typedef __attribute__((ext_vector_type(8))) short bf16x8;   // MFMA A/B operand (8 bf16)
typedef __attribute__((ext_vector_type(4))) float f32x4;    // MFMA C/D operand
typedef __attribute__((ext_vector_type(4))) unsigned int u32x4;
typedef __attribute__((ext_vector_type(8))) unsigned short u16x8;
typedef __attribute__((ext_vector_type(4))) unsigned short u16x4;

static __device__ __forceinline__ float bf2f(u16 u) {
    return __uint_as_float(((unsigned)u) << 16);
}
static __device__ __forceinline__ u16 f2bf(float f) {
    union { __hip_bfloat16 b; u16 u; } cv;
    cv.b = __float2bfloat16(f);
    return cv.u;
}
// async global->LDS, 16B per lane. LDS dest must be wave-uniform base + lane*16.
static __device__ __forceinline__ void gll16(const u16* gsrc, u16* ldst) {
    __builtin_amdgcn_global_load_lds(
        (const __attribute__((address_space(1))) unsigned int*)gsrc,
        (__attribute__((address_space(3))) unsigned int*)ldst, 16, 0, 0);
}

// ---------------- conversion kernels ----------------
__global__ __launch_bounds__(256) void cvt_bf(const float* __restrict__ in,
                                              u16* __restrict__ out, int n4) {
    int i = blockIdx.x * 256 + threadIdx.x;
    if (i < n4) {
        const float4 v = reinterpret_cast<const float4*>(in)[i];
        u16x4 o = { f2bf(v.x), f2bf(v.y), f2bf(v.z), f2bf(v.w) };
        *reinterpret_cast<u16x4*>(out + (long)i * 4) = o;
    }
}

// out[c][r] = bf16(in[r][c]); in is R x C row-major. grid (C/32, R/32), block (32,8)
__global__ void cvt_T(const float* __restrict__ in, u16* __restrict__ out, int R, int C) {
    __shared__ float tile[32][33];
    const int tx = threadIdx.x, ty = threadIdx.y;
    const int bx = blockIdx.x * 32, by = blockIdx.y * 32;
    #pragma unroll
    for (int i = 0; i < 32; i += 8)
        tile[ty + i][tx] = in[(long)(by + ty + i) * C + bx + tx];
    __syncthreads();
    #pragma unroll
    for (int i = 0; i < 32; i += 8)
        out[(long)(bx + ty + i) * R + by + tx] = f2bf(tile[tx][ty + i]);
}

// ---------------- generic MFMA GEMM (64x64 tile; kept for G3) ----------------
#define LDT 40
template<int EPI>
__global__ __launch_bounds__(256) void gemm_bt(
    const u16* __restrict__ A, int lda, long aBS,
    const u16* __restrict__ Bt, int ldb, long bBS,
    void* __restrict__ Cv, int ldc, long cBS,
    const float* __restrict__ bias, int biasBS, int K)
{
    __shared__ u16 As[64 * LDT];
    __shared__ u16 Bs[64 * LDT];
    const int t = threadIdx.x;
    const int z = blockIdx.z;
    const int mBase = blockIdx.y * 64, nBase = blockIdx.x * 64;
    const u16* Ab = A + (long)z * aBS;
    const u16* Bb = Bt + (long)z * bBS;
    const int lane = t & 63, w = t >> 6;
    const int r = t >> 2, seg = t & 3;
    f32x4 acc[4] = { {0.f,0.f,0.f,0.f}, {0.f,0.f,0.f,0.f}, {0.f,0.f,0.f,0.f}, {0.f,0.f,0.f,0.f} };
    const long aRow = (long)(mBase + r) * lda;
    const long bRow = (long)(nBase + r) * ldb;
    for (int k0 = 0; k0 < K; k0 += 32) {
        __syncthreads();
        *reinterpret_cast<u32x4*>(&As[r * LDT + seg * 8]) =
            *reinterpret_cast<const u32x4*>(&Ab[aRow + k0 + seg * 8]);
        *reinterpret_cast<u32x4*>(&Bs[r * LDT + seg * 8]) =
            *reinterpret_cast<const u32x4*>(&Bb[bRow + k0 + seg * 8]);
        __syncthreads();
        const bf16x8 af = *reinterpret_cast<const bf16x8*>(
            &As[(w * 16 + (lane & 15)) * LDT + (lane >> 4) * 8]);
        #pragma unroll
        for (int j = 0; j < 4; ++j) {
            const bf16x8 bfr = *reinterpret_cast<const bf16x8*>(
                &Bs[(j * 16 + (lane & 15)) * LDT + (lane >> 4) * 8]);
            acc[j] = __builtin_amdgcn_mfma_f32_16x16x32_bf16(af, bfr, acc[j], 0, 0, 0);
        }
    }
    const int rbase = mBase + w * 16 + ((lane >> 4) << 2);
    const int cb = nBase + (lane & 15);
    #pragma unroll
    for (int j = 0; j < 4; ++j) {
        const int col = cb + j * 16;
        const float badd = bias ? bias[(long)z * biasBS + col] : 0.f;
        #pragma unroll
        for (int i = 0; i < 4; ++i) {
            float v = acc[j][i] + badd;
            if (EPI == 2) v = 0.5f * v * (1.f + erff(v * 0.70710678118654752f));
            const long off = (long)z * cBS + (long)(rbase + i) * ldc + col;
            if (EPI == 1) reinterpret_cast<float*>(Cv)[off] = v;
            else          reinterpret_cast<u16*>(Cv)[off]  = f2bf(v);
        }
    }
}

// ---------------- 128x128-tile MFMA GEMM (m97 structure) for G1/G2/G4/G5 ----------------
// 256 threads = 4 waves in 2x2; per-wave 64x64 (acc[4][4]). BK=64.
// Staging via global_load_lds width=16, linear LDS dest; bank conflicts broken by a
// two-sided granule XOR swizzle (rule #21). 32 KB LDS, 2 barriers per K-step.
template<int EPI>
__global__ __launch_bounds__(256) void gemm128(
    const u16* __restrict__ A, int lda, long aZ,
    const u16* __restrict__ Bt, int ldb, long bZ,
    void* __restrict__ Cv, int ldc, long cZ,
    const float* __restrict__ bias, int K)
{
    __shared__ u16 As[128 * 64];
    __shared__ u16 Bs[128 * 64];
    const int t = threadIdx.x, lane = t & 63, w = t >> 6;
    const int z = blockIdx.z;
    const int mBase = blockIdx.y * 128, nBase = blockIdx.x * 128;
    const u16* Ab = A + (long)z * aZ;
    const u16* Bb = Bt + (long)z * bZ;
    const int wr = w >> 1, wc = w & 1;
    const int sr = lane >> 3, sg = lane & 7, sswz = sg ^ sr;   // staging row-in-8 / granule
    f32x4 acc[4][4];
    #pragma unroll
    for (int mi = 0; mi < 4; ++mi)
        #pragma unroll
        for (int ni = 0; ni < 4; ++ni) acc[mi][ni] = (f32x4){0.f, 0.f, 0.f, 0.f};

    for (int k0 = 0; k0 < K; k0 += 64) {
        #pragma unroll
        for (int i = 0; i < 4; ++i) {
            const int r = w * 32 + i * 8 + sr;                 // r&7 == sr
            gll16(&Ab[(long)(mBase + r) * lda + k0 + sswz * 8], &As[r * 64 + sg * 8]);
        }
        #pragma unroll
        for (int i = 0; i < 4; ++i) {
            const int r = w * 32 + i * 8 + sr;
            gll16(&Bb[(long)(nBase + r) * ldb + k0 + sswz * 8], &Bs[r * 64 + sg * 8]);
        }
        __syncthreads();   // drains vmcnt -> tiles ready
        #pragma unroll
        for (int ks = 0; ks < 2; ++ks) {
            bf16x8 aF[4], bF[4];
            #pragma unroll
            for (int mi = 0; mi < 4; ++mi) {
                const int rr = wr * 64 + mi * 16 + (lane & 15);
                aF[mi] = *reinterpret_cast<const bf16x8*>(
                    &As[rr * 64 + ((ks * 4 + (lane >> 4)) ^ (rr & 7)) * 8]);
            }
            #pragma unroll
            for (int ni = 0; ni < 4; ++ni) {
                const int rr = wc * 64 + ni * 16 + (lane & 15);
                bF[ni] = *reinterpret_cast<const bf16x8*>(
                    &Bs[rr * 64 + ((ks * 4 + (lane >> 4)) ^ (rr & 7)) * 8]);
            }
            #pragma unroll
            for (int mi = 0; mi < 4; ++mi)
                #pragma unroll
                for (int ni = 0; ni < 4; ++ni)
                    acc[mi][ni] = __builtin_amdgcn_mfma_f32_16x16x32_bf16(
                        aF[mi], bF[ni], acc[mi][ni], 0, 0, 0);
        }
        __syncthreads();   // all reads done before next overwrite
    }
    const int rb = mBase + wr * 64 + ((lane >> 4) << 2);
    const int cb = nBase + wc * 64 + (lane & 15);
    #pragma unroll
    for (int mi = 0; mi < 4; ++mi) {
        #pragma unroll
        for (int ni = 0; ni < 4; ++ni) {
            const int col = cb + ni * 16;
            const float badd = bias ? bias[col] : 0.f;
            #pragma unroll
            for (int i = 0; i < 4; ++i) {
                float v = acc[mi][ni][i] + badd;
                if (EPI == 2) v = 0.5f * v * (1.f + erff(v * 0.70710678118654752f));
                const long off = (long)z * cZ + (long)(rb + mi * 16 + i) * ldc + col;
                if (EPI == 1) reinterpret_cast<float*>(Cv)[off] = v;
                else          reinterpret_cast<u16*>(Cv)[off]  = f2bf(v);
            }
        }
    }
}

// ---------------- attention v4: split-K QK + cross-wave reduce, 2 blocks/CU ----------------
// Grid 512 blocks x 512 threads, NL=4 l's per block. Dynamic LDS = 80 KB exactly
// (tgtS 64K + red 16K) -> 2 blocks/CU; cross-block TLP hides the staging phases.
// Per l: stage target (proven swizzled layout); load this wave's 128-wide k-slice of
// qk[l] into 4 bf16x8 regs (pre-barrier -> no vmcnt FIFO hazard); QK = 8 MFMAs/wave
// (partial over k-slice); f32x4 cross-wave reduce in red[16][64] (each wave's partial
// has the SAME (d,h) lane map, so the sum preserves it); softmax + PV + tw store
// byte-identical to the round-5/7 proven code. MFMA/l drops 576->128 and qk is read
// once (not 8x).
#define NLV4 4
__global__ __launch_bounds__(512, 4) void attn_v4(
    const u16* __restrict__ qk,        // [L][H][DM] bf16
    const float* __restrict__ target,  // [L][D][DM] f32
    const float* __restrict__ mask,    // [L][D]     f32
    u16* __restrict__ tw)              // [L][H][DM] bf16
{
    extern __shared__ u16 smem[];
    u16*   tgtS = smem;                          // 32768 u16 = 64 KB
    f32x4* red  = (f32x4*)(smem + D * DM);       // 16 KB: [w*2+t][lane]

    const int t = threadIdx.x, lane = t & 63, w = t >> 6;
    const int g = lane >> 4, hm = lane & 15;
    const int l0 = blockIdx.x * NLV4;

    for (int li = 0; li < NLV4; ++li) {
        const int l = l0 + li;
        // ---- stage target[l] -> swizzled LDS (proven layout) ----
        const float* tl = target + (long)l * (D * DM);
        #pragma unroll
        for (int it = 0; it < 16; ++it) {
            const int i = it * 512 + t;
            const float4 v = reinterpret_cast<const float4*>(tl)[i];
            const int d = i >> 8, mm = (i & 255) * 4, cc = mm ^ ((d & 15) << 3);
            u16x4 o = { f2bf(v.x), f2bf(v.y), f2bf(v.z), f2bf(v.w) };
            *reinterpret_cast<u16x4*>(&tgtS[d * DM + cc]) = o;
        }
        // mask + this wave's qk k-slice -> regs (before barrier)
        const float* mrow = mask + (long)l * D;
        float mk[8];
        #pragma unroll
        for (int r = 0; r < 4; ++r) { mk[r] = mrow[4 * g + r]; mk[4 + r] = mrow[16 + 4 * g + r]; }
        const u16* qbase = qk + (long)l * (H * DM) + hm * DM + w * 128 + g * 8;
        bf16x8 qc[4];
        #pragma unroll
        for (int ks = 0; ks < 4; ++ks)
            qc[ks] = *reinterpret_cast<const bf16x8*>(&qbase[ks * 32]);
        __syncthreads();

        // ---- QK: partial scores over this wave's 128-k slice ----
        f32x4 a0 = {0.f, 0.f, 0.f, 0.f}, a1 = {0.f, 0.f, 0.f, 0.f};
        const int swz = hm << 3;
        #pragma unroll
        for (int ks = 0; ks < 4; ++ks) {
            const int mcol = w * 128 + ks * 32 + g * 8;
            const bf16x8 x0 = *reinterpret_cast<const bf16x8*>(&tgtS[hm * DM + (mcol ^ swz)]);
            const bf16x8 x1 = *reinterpret_cast<const bf16x8*>(&tgtS[(16 + hm) * DM + (mcol ^ swz)]);
            a0 = __builtin_amdgcn_mfma_f32_16x16x32_bf16(x0, qc[ks], a0, 0, 0, 0);
            a1 = __builtin_amdgcn_mfma_f32_16x16x32_bf16(x1, qc[ks], a1, 0, 0, 0);
        }
        red[(w * 2 + 0) * 64 + lane] = a0;
        red[(w * 2 + 1) * 64 + lane] = a1;
        __syncthreads();

        // ---- cross-wave reduce: full scores in every wave ----
        f32x4 s0 = red[lane], s1 = red[64 + lane];
        #pragma unroll
        for (int ww = 1; ww < 8; ++ww) {
            s0 += red[(ww * 2 + 0) * 64 + lane];
            s1 += red[(ww * 2 + 1) * 64 + lane];
        }

        // ---- softmax over d (lane holds d = {4g+r, 16+4g+r} for h = hm) ----
        float sc[8];
        #pragma unroll
        for (int r = 0; r < 4; ++r) {
            sc[r]     = s0[r] * 0.125f + mk[r];
            sc[4 + r] = s1[r] * 0.125f + mk[4 + r];
        }
        float mx = sc[0];
        #pragma unroll
        for (int r = 1; r < 8; ++r) mx = fmaxf(mx, sc[r]);
        mx = fmaxf(mx, __shfl_xor(mx, 16));
        mx = fmaxf(mx, __shfl_xor(mx, 32));
        float sum = 0.f;
        #pragma unroll
        for (int r = 0; r < 8; ++r) { sc[r] = __expf(sc[r] - mx); sum += sc[r]; }
        sum += __shfl_xor(sum, 16);
        sum += __shfl_xor(sum, 32);
        const float pinv = 1.0f / sum;
        bf16x8 pfrag;
        #pragma unroll
        for (int r = 0; r < 8; ++r) pfrag[r] = (short)f2bf(sc[r] * pinv);

        // ---- PV: 8 m-tiles per wave; A = tgt^T via scalar LDS reads, B = P ----
        u16* twl = tw + (long)l * (H * DM);
        const f32x4 zero = {0.f, 0.f, 0.f, 0.f};
        #pragma unroll
        for (int i = 0; i < 8; ++i) {
            const int mg = w * 8 + i;
            const int m = mg * 16 + hm;
            bf16x8 af;
            #pragma unroll
            for (int j = 0; j < 4; ++j) {
                const int d0 = 4 * g + j;
                const int d1 = 16 + 4 * g + j;
                af[j]     = (short)tgtS[d0 * DM + (m ^ (d0 << 3))];
                af[4 + j] = (short)tgtS[d1 * DM + (m ^ (d0 << 3))];
            }
            const f32x4 c = __builtin_amdgcn_mfma_f32_16x16x32_bf16(af, pfrag, zero, 0, 0, 0);
            u16x4 o = { f2bf(c[0]), f2bf(c[1]), f2bf(c[2]), f2bf(c[3]) };
            *reinterpret_cast<u16x4*>(&twl[hm * DM + mg * 16 + 4 * g]) = o;
        }
        __syncthreads();   // protect tgtS/red before next l
    }
}

// ---------------- fallback attention (r7 proven, 64 KB) ----------------
#define NLFB 8
__global__ __launch_bounds__(512) void attn_fb(
    const u16* __restrict__ qk, const float* __restrict__ target,
    const float* __restrict__ mask, u16* __restrict__ tw)
{
    extern __shared__ u16 smem[];
    u16* tgtS = smem;
    const int t = threadIdx.x, lane = t & 63, w = t >> 6;
    const int g = lane >> 4, hm = lane & 15;
    const int l0 = blockIdx.x * NLFB;
    float4 pf[16];
    {
        const float* tl = target + (long)l0 * (D * DM);
        #pragma unroll
        for (int it = 0; it < 16; ++it)
            pf[it] = reinterpret_cast<const float4*>(tl)[it * 512 + t];
    }
    for (int li = 0; li < NLFB; ++li) {
        const int l = l0 + li;
        #pragma unroll
        for (int it = 0; it < 16; ++it) {
            const int i = it * 512 + t;
            const int d = i >> 8, mm = (i & 255) * 4, cc = mm ^ ((d & 15) << 3);
            u16x4 o = { f2bf(pf[it].x), f2bf(pf[it].y), f2bf(pf[it].z), f2bf(pf[it].w) };
            *reinterpret_cast<u16x4*>(&tgtS[d * DM + cc]) = o;
        }
        const float* mrow = mask + (long)l * D;
        float mk[8];
        #pragma unroll
        for (int r = 0; r < 4; ++r) { mk[r] = mrow[4 * g + r]; mk[4 + r] = mrow[16 + 4 * g + r]; }
        __syncthreads();
        f32x4 acc0 = {0.f, 0.f, 0.f, 0.f}, acc1 = {0.f, 0.f, 0.f, 0.f};
        const u16* qrow = qk + (long)l * (H * DM) + hm * DM;
        const int swz = hm << 3;
        #pragma unroll 4
        for (int ks = 0; ks < 32; ++ks) {
            const int mcol = ks * 32 + g * 8;
            const bf16x8 yf = *reinterpret_cast<const bf16x8*>(&qrow[mcol]);
            const bf16x8 x0 = *reinterpret_cast<const bf16x8*>(&tgtS[hm * DM + (mcol ^ swz)]);
            const bf16x8 x1 = *reinterpret_cast<const bf16x8*>(&tgtS[(16 + hm) * DM + (mcol ^ swz)]);
            acc0 = __builtin_amdgcn_mfma_f32_16x16x32_bf16(x0, yf, acc0, 0, 0, 0);
            acc1 = __builtin_amdgcn_mfma_f32_16x16x32_bf16(x1, yf, acc1, 0, 0, 0);
        }
        if (li < NLFB - 1) {
            const float* tn = target + (long)(l + 1) * (D * DM);
            #pragma unroll
            for (int it = 0; it < 16; ++it)
                pf[it] = reinterpret_cast<const float4*>(tn)[it * 512 + t];
        }
        float sc[8];
        #pragma unroll
        for (int r = 0; r < 4; ++r) {
            sc[r]     = acc0[r] * 0.125f + mk[r];
            sc[4 + r] = acc1[r] * 0.125f + mk[4 + r];
        }
        float mx = sc[0];
        #pragma unroll
        for (int r = 1; r < 8; ++r) mx = fmaxf(mx, sc[r]);
        mx = fmaxf(mx, __shfl_xor(mx, 16));
        mx = fmaxf(mx, __shfl_xor(mx, 32));
        float sum = 0.f;
        #pragma unroll
        for (int r = 0; r < 8; ++r) { sc[r] = __expf(sc[r] - mx); sum += sc[r]; }
        sum += __shfl_xor(sum, 16);
        sum += __shfl_xor(sum, 32);
        const float pinv = 1.0f / sum;
        bf16x8 pfrag;
        #pragma unroll
        for (int r = 0; r < 8; ++r) pfrag[r] = (short)f2bf(sc[r] * pinv);
        u16* twl = tw + (long)l * (H * DM);
        const f32x4 zero = {0.f, 0.f, 0.f, 0.f};
        #pragma unroll
        for (int i = 0; i < 8; ++i) {
            const int mg = w * 8 + i;
            const int m = mg * 16 + hm;
            bf16x8 af;
            #pragma unroll
            for (int j = 0; j < 4; ++j) {
                const int d0 = 4 * g + j;
                const int d1 = 16 + 4 * g + j;
                af[j]     = (short)tgtS[d0 * DM + (m ^ (d0 << 3))];
                af[4 + j] = (short)tgtS[d1 * DM + (m ^ (d0 << 3))];
            }
            const f32x4 c = __builtin_amdgcn_mfma_f32_16x16x32_bf16(af, pfrag, zero, 0, 0, 0);
            u16x4 o = { f2bf(c[0]), f2bf(c[1]), f2bf(c[2]), f2bf(c[3]) };
            *reinterpret_cast<u16x4*>(&twl[hm * DM + mg * 16 + 4 * g]) = o;
        }
        __syncthreads();
    }
}

// ---------------- fused residual-add + LayerNorm (2 or 3 inputs + opt col bias) ----------------
__global__ __launch_bounds__(256) void ln_fuse(
    const float* __restrict__ a, const float* __restrict__ b,
    const float* __restrict__ c, const float* __restrict__ bvec,
    const float* __restrict__ g, const float* __restrict__ be,
    float* __restrict__ o32, u16* __restrict__ o16)
{
    const int l = blockIdx.x, t = threadIdx.x;
    __shared__ float S[4], SS[4];
    __shared__ float stats[2];
    const float4 va = reinterpret_cast<const float4*>(a + (long)l * DM)[t];
    const float4 vb = reinterpret_cast<const float4*>(b + (long)l * DM)[t];
    float v[4] = { va.x + vb.x, va.y + vb.y, va.z + vb.z, va.w + vb.w };
    if (c) {
        const float4 vc = reinterpret_cast<const float4*>(c + (long)l * DM)[t];
        v[0] += vc.x; v[1] += vc.y; v[2] += vc.z; v[3] += vc.w;
    }
    if (bvec) {
        const float4 vv = reinterpret_cast<const float4*>(bvec)[t];
        v[0] += vv.x; v[1] += vv.y; v[2] += vv.z; v[3] += vv.w;
    }
    float s  = v[0] + v[1] + v[2] + v[3];
    float ss = v[0]*v[0] + v[1]*v[1] + v[2]*v[2] + v[3]*v[3];
    #pragma unroll
    for (int off = 32; off; off >>= 1) { s += __shfl_down(s, off); ss += __shfl_down(ss, off); }
    if ((t & 63) == 0) { S[t >> 6] = s; SS[t >> 6] = ss; }
    __syncthreads();
    if (t == 0) {
        const float St  = S[0] + S[1] + S[2] + S[3];
        const float SSt = SS[0] + SS[1] + SS[2] + SS[3];
        const float mu  = St * (1.f / DM);
        const float var = fmaxf(SSt * (1.f / DM) - mu * mu, 0.f);
        stats[0] = mu;
        stats[1] = rsqrtf(var + 1e-5f);
    }
    __syncthreads();
    const float mu = stats[0], rs = stats[1];
    const int c0 = t * 4;
    float ov[4];
    #pragma unroll
    for (int j = 0; j < 4; ++j) ov[j] = (v[j] - mu) * rs * g[c0 + j] + be[c0 + j];
    float4 o; o.x = ov[0]; o.y = ov[1]; o.z = ov[2]; o.w = ov[3];
    reinterpret_cast<float4*>(o32 + (long)l * DM)[t] = o;
    if (o16) {
        u16x4 q = { f2bf(ov[0]), f2bf(ov[1]), f2bf(ov[2]), f2bf(ov[3]) };
        *reinterpret_cast<u16x4*>(o16 + (long)l * DM + c0) = q;
    }
}

// ---------------- launcher ----------------
extern "C" void kernel_launch(void* const* d_in, const int* in_sizes, int n_in,
                              void* d_out, int out_size, void* d_ws, size_t ws_size,
                              hipStream_t stream)
{
    const float* src    = (const float*)d_in[0];
    const float* target = (const float*)d_in[1];
    const float* amask  = (const float*)d_in[2];
    const float* Wq = (const float*)d_in[3];
    const float* bq = (const float*)d_in[4];
    const float* Wk = (const float*)d_in[5];
    const float* Wv = (const float*)d_in[7];
    const float* bv = (const float*)d_in[8];
    const float* W1 = (const float*)d_in[9];
    const float* b1 = (const float*)d_in[10];
    const float* W2 = (const float*)d_in[11];
    const float* b2 = (const float*)d_in[12];
    const float* g1  = (const float*)d_in[13];
    const float* be1 = (const float*)d_in[14];
    const float* g2  = (const float*)d_in[15];
    const float* be2 = (const float*)d_in[16];

    // Workspace arena (peak 158 MB). qk region (30..94) is dead after attn and re-used.
    char* ws = (char*)d_ws;
    const size_t MB = (size_t)1 << 20;
    u16*   src16 = (u16*)  (ws +  0 * MB);  //  4 MB  bf16(src)
    u16*   Wk16  = (u16*)  (ws +  4 * MB);  //  2 MB  bf16(Wk)
    u16*   WqT   = (u16*)  (ws +  6 * MB);  //  2 MB  bf16(Wq^T)
    u16*   WvT   = (u16*)  (ws +  8 * MB);  //  2 MB  bf16(Wv^T)
    u16*   W1T   = (u16*)  (ws + 10 * MB);  //  8 MB  bf16(W1^T)
    u16*   W2T   = (u16*)  (ws + 18 * MB);  //  8 MB  bf16(W2^T)
    u16*   Q16   = (u16*)  (ws + 26 * MB);  //  4 MB  q = src@Wq+bq
    u16*   qk16  = (u16*)  (ws + 30 * MB);  // 64 MB  qk[l,h,m]
    u16*   Y16   = (u16*)  (ws + 30 * MB);  // 16 MB  gelu(x@W1+b1)   [aliases dead qk]
    float* Z32   = (float*)(ws + 46 * MB);  //  8 MB  Y@W2 half z=0   [aliases dead qk]
    float* Z32b  = Z32 + (long)L * DM;      //  8 MB  Y@W2 half z=1 at ws+54MB (= Z32+cZ)
    float* ctx32 = (float*)(ws + 54 * MB);  //  8 MB  attention ctx   [dead after LN1]
    float* x32   = (float*)(ws + 62 * MB);  //  8 MB  LN1 out
    u16*   x16   = (u16*)  (ws + 70 * MB);  //  4 MB  bf16(x)
    u16*   tw16  = (u16*)  (ws + 94 * MB);  // 64 MB  softmax-weighted target sums

    cvt_bf<<<2048, 256, 0, stream>>>(src, src16, (L * DM) / 4);
    cvt_bf<<<1024, 256, 0, stream>>>(Wk, Wk16, (DM * DM) / 4);
    dim3 tb(32, 8);
    cvt_T<<<dim3(32, 32),  tb, 0, stream>>>(Wq, WqT, DM, DM);
    cvt_T<<<dim3(32, 32),  tb, 0, stream>>>(Wv, WvT, DM, DM);
    cvt_T<<<dim3(128, 32), tb, 0, stream>>>(W1, W1T, DM, FF);
    cvt_T<<<dim3(32, 128), tb, 0, stream>>>(W2, W2T, FF, DM);

    // G1: Q = bf16(src @ Wq + bq)   [128x128 tile]
    gemm128<0><<<dim3(DM / 128, L / 128, 1), 256, 0, stream>>>(
        src16, DM, 0, WqT, DM, 0, Q16, DM, 0, bq, DM);
    // G2 (batched over heads): qk[l,h,c] = sum_t Q[l,h,t] * Wk[c, h*64+t]   [128x128, K=64]
    gemm128<0><<<dim3(DM / 128, L / 128, H), 256, 0, stream>>>(
        Q16, DM, DH, Wk16, DM, DH, qk16, H * DM, DM, nullptr, DH);

    // fused MFMA attention: v4 (80 KB dynamic, 2 blocks/CU); fallback = r7 kernel
    (void)hipGetLastError();  // clear stale error
    (void)hipFuncSetAttribute(reinterpret_cast<const void*>(&attn_v4),
                              hipFuncAttributeMaxDynamicSharedMemorySize, 80 * 1024);
    attn_v4<<<L / NLV4, 512, 80 * 1024, stream>>>(qk16, target, amask, tw16);
    if (hipGetLastError() != hipSuccess) {
        attn_fb<<<L / NLFB, 512, 64 * 1024, stream>>>(qk16, target, amask, tw16);
    }

    // G3 (batched over heads): ctx[l, h*64+j] = sum_m tw[l,h,m] * Wv[m, h*64+j] + bv
    gemm_bt<1><<<dim3(1, L / 64, H), 256, 0, stream>>>(
        tw16, H * DM, DM, WvT, DM, (long)DH * DM, ctx32, DM, DH, bv, DH, DM);
    // x = LN(src + ctx)
    ln_fuse<<<L, 256, 0, stream>>>(src, ctx32, nullptr, nullptr, g1, be1, x32, x16);
    // G4: Y = bf16(gelu(x @ W1 + b1))   [128x128 tile]
    gemm128<2><<<dim3(FF / 128, L / 128, 1), 256, 0, stream>>>(
        x16, DM, 0, W1T, DM, 0, Y16, FF, 0, b1, DM);
    // G5: Z = Y @ W2 (f32), split-K z=2; halves at Z32 / Z32b = Z32 + L*DM
    gemm128<1><<<dim3(DM / 128, L / 128, 2), 256, 0, stream>>>(
        Y16, FF, 2048, W2T, FF, 2048, Z32, DM, (long)L * DM, nullptr, 2048);
    // out = LN(x + Za + Zb + b2)
    ln_fuse<<<L, 256, 0, stream>>>(x32, Z32, Z32b, b2, g2, be2, (float*)d_out, nullptr);
}

// Round 10
// 278.393 us; speedup vs baseline: 1.0917x; 1.0917x over previous
//
#include <hip/hip_runtime.h>
#include <hip/hip_bf16.h>

// Problem constants
#define L  2048
#define D  32
#define DM 1024
#define H  16
#define DH 64
#define FF 4096

typedef unsigned short u16;
typedef __attribute__((ext_vector_type(8))) short bf16x8;   // MFMA A/B operand (8 bf16)
typedef __attribute__((ext_vector_type(4))) float f32x4;    // MFMA C/D operand
typedef __attribute__((ext_vector_type(4))) unsigned int u32x4;
typedef __attribute__((ext_vector_type(8))) unsigned short u16x8;
typedef __attribute__((ext_vector_type(4))) unsigned short u16x4;

static __device__ __forceinline__ u16 f2bf(float f) {
    union { __hip_bfloat16 b; u16 u; } cv;
    cv.b = __float2bfloat16(f);
    return cv.u;
}
// async global->LDS, 16B per lane. LDS dest must be wave-uniform base + lane*16.
static __device__ __forceinline__ void gll16(const u16* gsrc, u16* ldst) {
    __builtin_amdgcn_global_load_lds(
        (const __attribute__((address_space(1))) unsigned int*)gsrc,
        (__attribute__((address_space(3))) unsigned int*)ldst, 16, 0, 0);
}

// ---------------- fused conversion kernels (2 launches total) ----------------
// blocks [0,2048): bf16(src); [2048,3072): bf16(Wk)
__global__ __launch_bounds__(256) void prep_bf(const float* __restrict__ a, u16* __restrict__ oa,
                                               const float* __restrict__ b, u16* __restrict__ ob) {
    const int i = blockIdx.x * 256 + threadIdx.x;
    const int na4 = (L * DM) / 4;
    const float* in;  u16* out;  int j;
    if (i < na4) { in = a; out = oa; j = i; }
    else         { in = b; out = ob; j = i - na4; }
    const float4 v = reinterpret_cast<const float4*>(in)[j];
    u16x4 o = { f2bf(v.x), f2bf(v.y), f2bf(v.z), f2bf(v.w) };
    *reinterpret_cast<u16x4*>(out + (long)j * 4) = o;
}

// fused 4-matrix transpose+cvt: out[c][r] = bf16(in[r][c]).
// flat blocks: [0,1024) Wq (1024x1024), [1024,2048) Wv, [2048,6144) W1 (1024x4096),
// [6144,10240) W2 (4096x1024). block (32,8).
__global__ void prep_T(const float* __restrict__ Wq, u16* __restrict__ oWq,
                       const float* __restrict__ Wv, u16* __restrict__ oWv,
                       const float* __restrict__ W1, u16* __restrict__ oW1,
                       const float* __restrict__ W2, u16* __restrict__ oW2) {
    __shared__ float tile[32][33];
    const int b = blockIdx.x;
    const float* in; u16* out; int R, C, bx, by;
    if (b < 1024)      { in = Wq; out = oWq; R = DM; C = DM; int bb = b;        bx = (bb & 31) * 32;  by = (bb >> 5) * 32; }
    else if (b < 2048) { in = Wv; out = oWv; R = DM; C = DM; int bb = b - 1024; bx = (bb & 31) * 32;  by = (bb >> 5) * 32; }
    else if (b < 6144) { in = W1; out = oW1; R = DM; C = FF; int bb = b - 2048; bx = (bb & 127) * 32; by = (bb >> 7) * 32; }
    else               { in = W2; out = oW2; R = FF; C = DM; int bb = b - 6144; bx = (bb & 31) * 32;  by = (bb >> 5) * 32; }
    const int tx = threadIdx.x, ty = threadIdx.y;
    #pragma unroll
    for (int i = 0; i < 32; i += 8)
        tile[ty + i][tx] = in[(long)(by + ty + i) * C + bx + tx];
    __syncthreads();
    #pragma unroll
    for (int i = 0; i < 32; i += 8)
        out[(long)(bx + ty + i) * R + by + tx] = f2bf(tile[tx][ty + i]);
}

// ---------------- 128xBN-tile MFMA GEMM (m97 structure) ----------------
// 256 threads = 4 waves in 2x2; per-wave 64 x BN/2 (acc[4][BN/32]). BK=64.
// Staging via global_load_lds width=16, linear LDS dest; bank conflicts broken by a
// two-sided granule XOR swizzle (rule #21). 2 barriers per K-step.
// EPI: 0 = bf16 store, 1 = f32 store, 2 = exact gelu -> bf16 store.
template<int EPI, int BN>
__global__ __launch_bounds__(256) void gemm128(
    const u16* __restrict__ A, int lda, long aZ,
    const u16* __restrict__ Bt, int ldb, long bZ,
    void* __restrict__ Cv, int ldc, long cZ,
    const float* __restrict__ bias, int biasZ, int K)
{
    constexpr int NI = BN / 32;          // B-frags per wave / stage iters
    __shared__ u16 As[128 * 64];
    __shared__ u16 Bs[BN * 64];
    const int t = threadIdx.x, lane = t & 63, w = t >> 6;
    const int z = blockIdx.z;
    const int mBase = blockIdx.y * 128, nBase = blockIdx.x * BN;
    const u16* Ab = A + (long)z * aZ;
    const u16* Bb = Bt + (long)z * bZ;
    const int wr = w >> 1, wc = w & 1;
    const int sr = lane >> 3, sg = lane & 7, sswz = sg ^ sr;   // staging row-in-8 / granule
    f32x4 acc[4][NI];
    #pragma unroll
    for (int mi = 0; mi < 4; ++mi)
        #pragma unroll
        for (int ni = 0; ni < NI; ++ni) acc[mi][ni] = (f32x4){0.f, 0.f, 0.f, 0.f};

    for (int k0 = 0; k0 < K; k0 += 64) {
        #pragma unroll
        for (int i = 0; i < 4; ++i) {
            const int r = w * 32 + i * 8 + sr;                 // r&7 == sr
            gll16(&Ab[(long)(mBase + r) * lda + k0 + sswz * 8], &As[r * 64 + sg * 8]);
        }
        #pragma unroll
        for (int i = 0; i < NI; ++i) {
            const int r = w * (BN / 4) + i * 8 + sr;
            gll16(&Bb[(long)(nBase + r) * ldb + k0 + sswz * 8], &Bs[r * 64 + sg * 8]);
        }
        __syncthreads();   // drains vmcnt -> tiles ready
        #pragma unroll
        for (int ks = 0; ks < 2; ++ks) {
            bf16x8 aF[4], bF[NI];
            #pragma unroll
            for (int mi = 0; mi < 4; ++mi) {
                const int rr = wr * 64 + mi * 16 + (lane & 15);
                aF[mi] = *reinterpret_cast<const bf16x8*>(
                    &As[rr * 64 + ((ks * 4 + (lane >> 4)) ^ (rr & 7)) * 8]);
            }
            #pragma unroll
            for (int ni = 0; ni < NI; ++ni) {
                const int rr = wc * (BN / 2) + ni * 16 + (lane & 15);
                bF[ni] = *reinterpret_cast<const bf16x8*>(
                    &Bs[rr * 64 + ((ks * 4 + (lane >> 4)) ^ (rr & 7)) * 8]);
            }
            #pragma unroll
            for (int mi = 0; mi < 4; ++mi)
                #pragma unroll
                for (int ni = 0; ni < NI; ++ni)
                    acc[mi][ni] = __builtin_amdgcn_mfma_f32_16x16x32_bf16(
                        aF[mi], bF[ni], acc[mi][ni], 0, 0, 0);
        }
        __syncthreads();   // all reads done before next overwrite
    }
    const int rb = mBase + wr * 64 + ((lane >> 4) << 2);
    const int cb = nBase + wc * (BN / 2) + (lane & 15);
    #pragma unroll
    for (int mi = 0; mi < 4; ++mi) {
        #pragma unroll
        for (int ni = 0; ni < NI; ++ni) {
            const int col = cb + ni * 16;
            const float badd = bias ? bias[(long)z * biasZ + col] : 0.f;
            #pragma unroll
            for (int i = 0; i < 4; ++i) {
                float v = acc[mi][ni][i] + badd;
                if (EPI == 2) v = 0.5f * v * (1.f + erff(v * 0.70710678118654752f));
                const long off = (long)z * cZ + (long)(rb + mi * 16 + i) * ldc + col;
                if (EPI == 1) reinterpret_cast<float*>(Cv)[off] = v;
                else          reinterpret_cast<u16*>(Cv)[off]  = f2bf(v);
            }
        }
    }
}

// ---------------- attention v5: LDS double-buffer pipeline ----------------
// Grid 256 x 512 threads, NL=8 l's per block, 1 block/CU. Dynamic LDS = 144 KB:
// tgtS0/tgtS1 (64K each, proven swizzled layout) + red (16K).
// Schedule per l (2 barriers): [stage-write l+1 into other buffer (consumes pf,
// issued one iter ago) | issue pf loads l+2 | load qc(l+1)] -> QK(l) from cur buffer
// -> red write -> barrier -> reduce -> softmax -> PV(l) -> tw store -> barrier.
// Stage-writes overlap compute (disjoint buffers); HBM loads fly across the whole
// compute phase. Math identical to the round-7/8 passing kernels.
#define NLV5 8
__global__ __launch_bounds__(512, 2) void attn_v5(
    const u16* __restrict__ qk,        // [L][H][DM] bf16
    const float* __restrict__ target,  // [L][D][DM] f32
    const float* __restrict__ mask,    // [L][D]     f32
    u16* __restrict__ tw)              // [L][H][DM] bf16
{
    extern __shared__ u16 smem[];
    u16*   tgtS0 = smem;                         // 32768 u16
    u16*   tgtS1 = smem + D * DM;                // 32768 u16
    f32x4* red   = (f32x4*)(smem + 2 * D * DM);  // 16 KB: [w*2+t][lane]

    const int t = threadIdx.x, lane = t & 63, w = t >> 6;
    const int g = lane >> 4, hm = lane & 15;
    const int l0 = blockIdx.x * NLV5;

    float4 pf[16];
    bf16x8 qc[2][4];   // double-buffered qk k-slices; [li&1] is current
    // ---- prologue: stage l0 into tgtS0; prefetch pf(l0+1), qc[0](l0) ----
    {
        const float* tl = target + (long)l0 * (D * DM);
        #pragma unroll
        for (int it = 0; it < 16; ++it)
            pf[it] = reinterpret_cast<const float4*>(tl)[it * 512 + t];
        #pragma unroll
        for (int it = 0; it < 16; ++it) {
            const int i = it * 512 + t;
            const int d = i >> 8, mm = (i & 255) * 4, cc = mm ^ ((d & 15) << 3);
            u16x4 o = { f2bf(pf[it].x), f2bf(pf[it].y), f2bf(pf[it].z), f2bf(pf[it].w) };
            *reinterpret_cast<u16x4*>(&tgtS0[d * DM + cc]) = o;
        }
        const float* tn = target + (long)(l0 + 1) * (D * DM);
        #pragma unroll
        for (int it = 0; it < 16; ++it)
            pf[it] = reinterpret_cast<const float4*>(tn)[it * 512 + t];
        const u16* qb = qk + (long)l0 * (H * DM) + hm * DM + w * 128 + g * 8;
        #pragma unroll
        for (int ks = 0; ks < 4; ++ks)
            qc[0][ks] = *reinterpret_cast<const bf16x8*>(&qb[ks * 32]);
    }
    __syncthreads();

    #pragma unroll
    for (int li = 0; li < NLV5; ++li) {
        const int l = l0 + li;
        const int cur = li & 1, nxt = cur ^ 1;
        u16* curS = cur ? tgtS1 : tgtS0;
        u16* nxtS = cur ? tgtS0 : tgtS1;

        const float* mrow = mask + (long)l * D;
        float mk[8];
        #pragma unroll
        for (int r = 0; r < 4; ++r) { mk[r] = mrow[4 * g + r]; mk[4 + r] = mrow[16 + 4 * g + r]; }

        if (li < NLV5 - 1) {
            // stage-write l+1 (consumes pf; overlaps this l's compute — disjoint buffer)
            #pragma unroll
            for (int it = 0; it < 16; ++it) {
                const int i = it * 512 + t;
                const int d = i >> 8, mm = (i & 255) * 4, cc = mm ^ ((d & 15) << 3);
                u16x4 o = { f2bf(pf[it].x), f2bf(pf[it].y), f2bf(pf[it].z), f2bf(pf[it].w) };
                *reinterpret_cast<u16x4*>(&nxtS[d * DM + cc]) = o;
            }
            if (li < NLV5 - 2) {
                const float* tn = target + (long)(l + 2) * (D * DM);
                #pragma unroll
                for (int it = 0; it < 16; ++it)
                    pf[it] = reinterpret_cast<const float4*>(tn)[it * 512 + t];
            }
            const u16* qn = qk + (long)(l + 1) * (H * DM) + hm * DM + w * 128 + g * 8;
            #pragma unroll
            for (int ks = 0; ks < 4; ++ks)
                qc[nxt][ks] = *reinterpret_cast<const bf16x8*>(&qn[ks * 32]);
        }

        // ---- QK: partial scores over this wave's 128-k slice (proven map) ----
        f32x4 a0 = {0.f, 0.f, 0.f, 0.f}, a1 = {0.f, 0.f, 0.f, 0.f};
        const int swz = hm << 3;
        #pragma unroll
        for (int ks = 0; ks < 4; ++ks) {
            const int mcol = w * 128 + ks * 32 + g * 8;
            const bf16x8 x0 = *reinterpret_cast<const bf16x8*>(&curS[hm * DM + (mcol ^ swz)]);
            const bf16x8 x1 = *reinterpret_cast<const bf16x8*>(&curS[(16 + hm) * DM + (mcol ^ swz)]);
            a0 = __builtin_amdgcn_mfma_f32_16x16x32_bf16(x0, qc[cur][ks], a0, 0, 0, 0);
            a1 = __builtin_amdgcn_mfma_f32_16x16x32_bf16(x1, qc[cur][ks], a1, 0, 0, 0);
        }
        red[(w * 2 + 0) * 64 + lane] = a0;
        red[(w * 2 + 1) * 64 + lane] = a1;
        __syncthreads();

        f32x4 s0 = red[lane], s1 = red[64 + lane];
        #pragma unroll
        for (int ww = 1; ww < 8; ++ww) {
            s0 += red[(ww * 2 + 0) * 64 + lane];
            s1 += red[(ww * 2 + 1) * 64 + lane];
        }

        // ---- softmax over d (lane holds d = {4g+r, 16+4g+r} for h = hm) ----
        float sc[8];
        #pragma unroll
        for (int r = 0; r < 4; ++r) {
            sc[r]     = s0[r] * 0.125f + mk[r];
            sc[4 + r] = s1[r] * 0.125f + mk[4 + r];
        }
        float mx = sc[0];
        #pragma unroll
        for (int r = 1; r < 8; ++r) mx = fmaxf(mx, sc[r]);
        mx = fmaxf(mx, __shfl_xor(mx, 16));
        mx = fmaxf(mx, __shfl_xor(mx, 32));
        float sum = 0.f;
        #pragma unroll
        for (int r = 0; r < 8; ++r) { sc[r] = __expf(sc[r] - mx); sum += sc[r]; }
        sum += __shfl_xor(sum, 16);
        sum += __shfl_xor(sum, 32);
        const float pinv = 1.0f / sum;
        bf16x8 pfrag;
        #pragma unroll
        for (int r = 0; r < 8; ++r) pfrag[r] = (short)f2bf(sc[r] * pinv);

        // ---- PV: 8 m-tiles per wave; A = tgt^T via scalar LDS reads, B = P ----
        u16* twl = tw + (long)l * (H * DM);
        const f32x4 zero = {0.f, 0.f, 0.f, 0.f};
        #pragma unroll
        for (int i = 0; i < 8; ++i) {
            const int mg = w * 8 + i;
            const int m = mg * 16 + hm;
            bf16x8 af;
            #pragma unroll
            for (int j = 0; j < 4; ++j) {
                const int d0 = 4 * g + j;
                const int d1 = 16 + 4 * g + j;
                af[j]     = (short)curS[d0 * DM + (m ^ (d0 << 3))];
                af[4 + j] = (short)curS[d1 * DM + (m ^ (d0 << 3))];
            }
            const f32x4 c = __builtin_amdgcn_mfma_f32_16x16x32_bf16(af, pfrag, zero, 0, 0, 0);
            u16x4 o = { f2bf(c[0]), f2bf(c[1]), f2bf(c[2]), f2bf(c[3]) };
            *reinterpret_cast<u16x4*>(&twl[hm * DM + mg * 16 + 4 * g]) = o;
        }
        __syncthreads();   // all reads of curS/red done -> next iter may overwrite
    }
}

// ---------------- fused residual-add + LayerNorm (2 or 3 inputs + opt col bias) ----------------
__global__ __launch_bounds__(256) void ln_fuse(
    const float* __restrict__ a, const float* __restrict__ b,
    const float* __restrict__ c, const float* __restrict__ bvec,
    const float* __restrict__ g, const float* __restrict__ be,
    float* __restrict__ o32, u16* __restrict__ o16)
{
    const int l = blockIdx.x, t = threadIdx.x;
    __shared__ float S[4], SS[4];
    __shared__ float stats[2];
    const float4 va = reinterpret_cast<const float4*>(a + (long)l * DM)[t];
    const float4 vb = reinterpret_cast<const float4*>(b + (long)l * DM)[t];
    float v[4] = { va.x + vb.x, va.y + vb.y, va.z + vb.z, va.w + vb.w };
    if (c) {
        const float4 vc = reinterpret_cast<const float4*>(c + (long)l * DM)[t];
        v[0] += vc.x; v[1] += vc.y; v[2] += vc.z; v[3] += vc.w;
    }
    if (bvec) {
        const float4 vv = reinterpret_cast<const float4*>(bvec)[t];
        v[0] += vv.x; v[1] += vv.y; v[2] += vv.z; v[3] += vv.w;
    }
    float s  = v[0] + v[1] + v[2] + v[3];
    float ss = v[0]*v[0] + v[1]*v[1] + v[2]*v[2] + v[3]*v[3];
    #pragma unroll
    for (int off = 32; off; off >>= 1) { s += __shfl_down(s, off); ss += __shfl_down(ss, off); }
    if ((t & 63) == 0) { S[t >> 6] = s; SS[t >> 6] = ss; }
    __syncthreads();
    if (t == 0) {
        const float St  = S[0] + S[1] + S[2] + S[3];
        const float SSt = SS[0] + SS[1] + SS[2] + SS[3];
        const float mu  = St * (1.f / DM);
        const float var = fmaxf(SSt * (1.f / DM) - mu * mu, 0.f);
        stats[0] = mu;
        stats[1] = rsqrtf(var + 1e-5f);
    }
    __syncthreads();
    const float mu = stats[0], rs = stats[1];
    const int c0 = t * 4;
    float ov[4];
    #pragma unroll
    for (int j = 0; j < 4; ++j) ov[j] = (v[j] - mu) * rs * g[c0 + j] + be[c0 + j];
    float4 o; o.x = ov[0]; o.y = ov[1]; o.z = ov[2]; o.w = ov[3];
    reinterpret_cast<float4*>(o32 + (long)l * DM)[t] = o;
    if (o16) {
        u16x4 q = { f2bf(ov[0]), f2bf(ov[1]), f2bf(ov[2]), f2bf(ov[3]) };
        *reinterpret_cast<u16x4*>(o16 + (long)l * DM + c0) = q;
    }
}

// ---------------- launcher ----------------
extern "C" void kernel_launch(void* const* d_in, const int* in_sizes, int n_in,
                              void* d_out, int out_size, void* d_ws, size_t ws_size,
                              hipStream_t stream)
{
    const float* src    = (const float*)d_in[0];
    const float* target = (const float*)d_in[1];
    const float* amask  = (const float*)d_in[2];
    const float* Wq = (const float*)d_in[3];
    const float* bq = (const float*)d_in[4];
    const float* Wk = (const float*)d_in[5];
    const float* Wv = (const float*)d_in[7];
    const float* bv = (const float*)d_in[8];
    const float* W1 = (const float*)d_in[9];
    const float* b1 = (const float*)d_in[10];
    const float* W2 = (const float*)d_in[11];
    const float* b2 = (const float*)d_in[12];
    const float* g1  = (const float*)d_in[13];
    const float* be1 = (const float*)d_in[14];
    const float* g2  = (const float*)d_in[15];
    const float* be2 = (const float*)d_in[16];

    // Workspace arena (peak 158 MB). qk region (30..94) is dead after attn and re-used.
    char* ws = (char*)d_ws;
    const size_t MB = (size_t)1 << 20;
    u16*   src16 = (u16*)  (ws +  0 * MB);  //  4 MB  bf16(src)
    u16*   Wk16  = (u16*)  (ws +  4 * MB);  //  2 MB  bf16(Wk)
    u16*   WqT   = (u16*)  (ws +  6 * MB);  //  2 MB  bf16(Wq^T)
    u16*   WvT   = (u16*)  (ws +  8 * MB);  //  2 MB  bf16(Wv^T)
    u16*   W1T   = (u16*)  (ws + 10 * MB);  //  8 MB  bf16(W1^T)
    u16*   W2T   = (u16*)  (ws + 18 * MB);  //  8 MB  bf16(W2^T)
    u16*   Q16   = (u16*)  (ws + 26 * MB);  //  4 MB  q = src@Wq+bq
    u16*   qk16  = (u16*)  (ws + 30 * MB);  // 64 MB  qk[l,h,m]
    u16*   Y16   = (u16*)  (ws + 30 * MB);  // 16 MB  gelu(x@W1+b1)   [aliases dead qk]
    float* Z32   = (float*)(ws + 46 * MB);  //  8 MB  Y@W2 half z=0   [aliases dead qk]
    float* Z32b  = Z32 + (long)L * DM;      //  8 MB  Y@W2 half z=1 at ws+54MB (= Z32+cZ)
    float* ctx32 = (float*)(ws + 54 * MB);  //  8 MB  attention ctx   [dead after LN1]
    float* x32   = (float*)(ws + 62 * MB);  //  8 MB  LN1 out
    u16*   x16   = (u16*)  (ws + 70 * MB);  //  4 MB  bf16(x)
    u16*   tw16  = (u16*)  (ws + 94 * MB);  // 64 MB  softmax-weighted target sums

    // conversions (2 fused launches)
    prep_bf<<<3072, 256, 0, stream>>>(src, src16, Wk, Wk16);
    prep_T<<<10240, dim3(32, 8), 0, stream>>>(Wq, WqT, Wv, WvT, W1, W1T, W2, W2T);

    // G1: Q = bf16(src @ Wq + bq)
    gemm128<0, 128><<<dim3(DM / 128, L / 128, 1), 256, 0, stream>>>(
        src16, DM, 0, WqT, DM, 0, Q16, DM, 0, bq, 0, DM);
    // G2 (batched over heads): qk[l,h,c] = sum_t Q[l,h,t] * Wk[c, h*64+t]   (K=64)
    gemm128<0, 128><<<dim3(DM / 128, L / 128, H), 256, 0, stream>>>(
        Q16, DM, DH, Wk16, DM, DH, qk16, H * DM, DM, nullptr, 0, DH);

    // fused MFMA attention (144 KB dynamic LDS double-buffer pipeline; r3 proved
    // the >64KB dynamic-LDS path launches correctly with the attribute set)
    (void)hipFuncSetAttribute(reinterpret_cast<const void*>(&attn_v5),
                              hipFuncAttributeMaxDynamicSharedMemorySize, 144 * 1024);
    attn_v5<<<L / NLV5, 512, 144 * 1024, stream>>>(qk16, target, amask, tw16);

    // G3 (batched over heads): ctx[l, h*64+j] = sum_m tw[l,h,m] * Wv[m, h*64+j] + bv
    gemm128<1, 64><<<dim3(1, L / 128, H), 256, 0, stream>>>(
        tw16, H * DM, DM, WvT, DM, (long)DH * DM, ctx32, DM, DH, bv, DH, DM);
    // x = LN(src + ctx)
    ln_fuse<<<L, 256, 0, stream>>>(src, ctx32, nullptr, nullptr, g1, be1, x32, x16);
    // G4: Y = bf16(gelu(x @ W1 + b1))
    gemm128<2, 128><<<dim3(FF / 128, L / 128, 1), 256, 0, stream>>>(
        x16, DM, 0, W1T, DM, 0, Y16, FF, 0, b1, 0, DM);
    // G5: Z = Y @ W2 (f32), split-K z=2; halves at Z32 / Z32b = Z32 + L*DM
    gemm128<1, 128><<<dim3(DM / 128, L / 128, 2), 256, 0, stream>>>(
        Y16, FF, 2048, W2T, FF, 2048, Z32, DM, (long)L * DM, nullptr, 0, 2048);
    // out = LN(x + Za + Zb + b2)
    ln_fuse<<<L, 256, 0, stream>>>(x32, Z32, Z32b, b2, g2, be2, (float*)d_out, nullptr);
}

// Round 11
// 250.807 us; speedup vs baseline: 1.2117x; 1.1100x over previous
//
#include <hip/hip_runtime.h>
#include <hip/hip_bf16.h>

// Problem constants
#define L  2048
#define D  32
#define DM 1024
#define H  16
#define DH 64
#define FF 4096

typedef unsigned short u16;
typedef __attribute__((ext_vector_type(8))) short bf16x8;   // MFMA A/B operand (8 bf16)
typedef __attribute__((ext_vector_type(4))) float f32x4;    // MFMA C/D operand
typedef __attribute__((ext_vector_type(4))) unsigned int u32x4;
typedef __attribute__((ext_vector_type(8))) unsigned short u16x8;
typedef __attribute__((ext_vector_type(4))) unsigned short u16x4;

static __device__ __forceinline__ u16 f2bf(float f) {
    union { __hip_bfloat16 b; u16 u; } cv;
    cv.b = __float2bfloat16(f);
    return cv.u;
}
// async global->LDS, 16B per lane. LDS dest must be wave-uniform base + lane*16.
static __device__ __forceinline__ void gll16(const u16* gsrc, u16* ldst) {
    __builtin_amdgcn_global_load_lds(
        (const __attribute__((address_space(1))) unsigned int*)gsrc,
        (__attribute__((address_space(3))) unsigned int*)ldst, 16, 0, 0);
}

// ---------------- fused conversion kernels (2 launches total) ----------------
// blocks [0,2048): bf16(src); [2048,3072): bf16(Wk)
__global__ __launch_bounds__(256) void prep_bf(const float* __restrict__ a, u16* __restrict__ oa,
                                               const float* __restrict__ b, u16* __restrict__ ob) {
    const int i = blockIdx.x * 256 + threadIdx.x;
    const int na4 = (L * DM) / 4;
    const float* in;  u16* out;  int j;
    if (i < na4) { in = a; out = oa; j = i; }
    else         { in = b; out = ob; j = i - na4; }
    const float4 v = reinterpret_cast<const float4*>(in)[j];
    u16x4 o = { f2bf(v.x), f2bf(v.y), f2bf(v.z), f2bf(v.w) };
    *reinterpret_cast<u16x4*>(out + (long)j * 4) = o;
}

// fused 4-matrix transpose+cvt: out[c][r] = bf16(in[r][c]).
// flat blocks: [0,1024) Wq (1024x1024), [1024,2048) Wv, [2048,6144) W1 (1024x4096),
// [6144,10240) W2 (4096x1024). block (32,8).
__global__ void prep_T(const float* __restrict__ Wq, u16* __restrict__ oWq,
                       const float* __restrict__ Wv, u16* __restrict__ oWv,
                       const float* __restrict__ W1, u16* __restrict__ oW1,
                       const float* __restrict__ W2, u16* __restrict__ oW2) {
    __shared__ float tile[32][33];
    const int b = blockIdx.x;
    const float* in; u16* out; int R, C, bx, by;
    if (b < 1024)      { in = Wq; out = oWq; R = DM; C = DM; int bb = b;        bx = (bb & 31) * 32;  by = (bb >> 5) * 32; }
    else if (b < 2048) { in = Wv; out = oWv; R = DM; C = DM; int bb = b - 1024; bx = (bb & 31) * 32;  by = (bb >> 5) * 32; }
    else if (b < 6144) { in = W1; out = oW1; R = DM; C = FF; int bb = b - 2048; bx = (bb & 127) * 32; by = (bb >> 7) * 32; }
    else               { in = W2; out = oW2; R = FF; C = DM; int bb = b - 6144; bx = (bb & 31) * 32;  by = (bb >> 5) * 32; }
    const int tx = threadIdx.x, ty = threadIdx.y;
    #pragma unroll
    for (int i = 0; i < 32; i += 8)
        tile[ty + i][tx] = in[(long)(by + ty + i) * C + bx + tx];
    __syncthreads();
    #pragma unroll
    for (int i = 0; i < 32; i += 8)
        out[(long)(bx + ty + i) * R + by + tx] = f2bf(tile[tx][ty + i]);
}

// ---------------- 128xBN-tile MFMA GEMM (m97 structure) ----------------
// 256 threads = 4 waves in 2x2; per-wave 64 x BN/2 (acc[4][BN/32]). BK=64.
// Staging via global_load_lds width=16, linear LDS dest; bank conflicts broken by a
// two-sided granule XOR swizzle (rule #21). 2 barriers per K-step.
// XCD-aware bijective block swizzle in the xy-plane (requires gridDim.x*gridDim.y % 8 == 0
// — true for every launch below): consecutive work tiles stay on one XCD's L2.
// EPI: 0 = bf16 store, 1 = f32 store, 2 = exact gelu -> bf16 store.
template<int EPI, int BN>
__global__ __launch_bounds__(256) void gemm128(
    const u16* __restrict__ A, int lda, long aZ,
    const u16* __restrict__ Bt, int ldb, long bZ,
    void* __restrict__ Cv, int ldc, long cZ,
    const float* __restrict__ bias, int biasZ, int K)
{
    constexpr int NI = BN / 32;          // B-frags per wave / stage iters
    __shared__ u16 As[128 * 64];
    __shared__ u16 Bs[BN * 64];
    const int t = threadIdx.x, lane = t & 63, w = t >> 6;
    const int z = blockIdx.z;
    // XCD swizzle: hardware block b (XCD = b%8) -> contiguous work chunk per XCD
    const int nxy = gridDim.x * gridDim.y;
    int fid = blockIdx.y * gridDim.x + blockIdx.x;
    const int q8 = nxy >> 3;
    fid = (fid & 7) * q8 + (fid >> 3);
    const int bx = fid % gridDim.x, by = fid / gridDim.x;
    const int mBase = by * 128, nBase = bx * BN;
    const u16* Ab = A + (long)z * aZ;
    const u16* Bb = Bt + (long)z * bZ;
    const int wr = w >> 1, wc = w & 1;
    const int sr = lane >> 3, sg = lane & 7, sswz = sg ^ sr;   // staging row-in-8 / granule
    f32x4 acc[4][NI];
    #pragma unroll
    for (int mi = 0; mi < 4; ++mi)
        #pragma unroll
        for (int ni = 0; ni < NI; ++ni) acc[mi][ni] = (f32x4){0.f, 0.f, 0.f, 0.f};

    for (int k0 = 0; k0 < K; k0 += 64) {
        #pragma unroll
        for (int i = 0; i < 4; ++i) {
            const int r = w * 32 + i * 8 + sr;                 // r&7 == sr
            gll16(&Ab[(long)(mBase + r) * lda + k0 + sswz * 8], &As[r * 64 + sg * 8]);
        }
        #pragma unroll
        for (int i = 0; i < NI; ++i) {
            const int r = w * (BN / 4) + i * 8 + sr;
            gll16(&Bb[(long)(nBase + r) * ldb + k0 + sswz * 8], &Bs[r * 64 + sg * 8]);
        }
        __syncthreads();   // drains vmcnt -> tiles ready
        #pragma unroll
        for (int ks = 0; ks < 2; ++ks) {
            bf16x8 aF[4], bF[NI];
            #pragma unroll
            for (int mi = 0; mi < 4; ++mi) {
                const int rr = wr * 64 + mi * 16 + (lane & 15);
                aF[mi] = *reinterpret_cast<const bf16x8*>(
                    &As[rr * 64 + ((ks * 4 + (lane >> 4)) ^ (rr & 7)) * 8]);
            }
            #pragma unroll
            for (int ni = 0; ni < NI; ++ni) {
                const int rr = wc * (BN / 2) + ni * 16 + (lane & 15);
                bF[ni] = *reinterpret_cast<const bf16x8*>(
                    &Bs[rr * 64 + ((ks * 4 + (lane >> 4)) ^ (rr & 7)) * 8]);
            }
            #pragma unroll
            for (int mi = 0; mi < 4; ++mi)
                #pragma unroll
                for (int ni = 0; ni < NI; ++ni)
                    acc[mi][ni] = __builtin_amdgcn_mfma_f32_16x16x32_bf16(
                        aF[mi], bF[ni], acc[mi][ni], 0, 0, 0);
        }
        __syncthreads();   // all reads done before next overwrite
    }
    const int rb = mBase + wr * 64 + ((lane >> 4) << 2);
    const int cb = nBase + wc * (BN / 2) + (lane & 15);
    #pragma unroll
    for (int mi = 0; mi < 4; ++mi) {
        #pragma unroll
        for (int ni = 0; ni < NI; ++ni) {
            const int col = cb + ni * 16;
            const float badd = bias ? bias[(long)z * biasZ + col] : 0.f;
            #pragma unroll
            for (int i = 0; i < 4; ++i) {
                float v = acc[mi][ni][i] + badd;
                if (EPI == 2) v = 0.5f * v * (1.f + erff(v * 0.70710678118654752f));
                const long off = (long)z * cZ + (long)(rb + mi * 16 + i) * ldc + col;
                if (EPI == 1) reinterpret_cast<float*>(Cv)[off] = v;
                else          reinterpret_cast<u16*>(Cv)[off]  = f2bf(v);
            }
        }
    }
}

// ---------------- attention v5: LDS double-buffer pipeline (r10 passing, unchanged) ----------------
#define NLV5 8
__global__ __launch_bounds__(512, 2) void attn_v5(
    const u16* __restrict__ qk,        // [L][H][DM] bf16
    const float* __restrict__ target,  // [L][D][DM] f32
    const float* __restrict__ mask,    // [L][D]     f32
    u16* __restrict__ tw)              // [L][H][DM] bf16
{
    extern __shared__ u16 smem[];
    u16*   tgtS0 = smem;                         // 32768 u16
    u16*   tgtS1 = smem + D * DM;                // 32768 u16
    f32x4* red   = (f32x4*)(smem + 2 * D * DM);  // 16 KB: [w*2+t][lane]

    const int t = threadIdx.x, lane = t & 63, w = t >> 6;
    const int g = lane >> 4, hm = lane & 15;
    const int l0 = blockIdx.x * NLV5;

    float4 pf[16];
    bf16x8 qc[2][4];   // double-buffered qk k-slices; [li&1] is current
    {
        const float* tl = target + (long)l0 * (D * DM);
        #pragma unroll
        for (int it = 0; it < 16; ++it)
            pf[it] = reinterpret_cast<const float4*>(tl)[it * 512 + t];
        #pragma unroll
        for (int it = 0; it < 16; ++it) {
            const int i = it * 512 + t;
            const int d = i >> 8, mm = (i & 255) * 4, cc = mm ^ ((d & 15) << 3);
            u16x4 o = { f2bf(pf[it].x), f2bf(pf[it].y), f2bf(pf[it].z), f2bf(pf[it].w) };
            *reinterpret_cast<u16x4*>(&tgtS0[d * DM + cc]) = o;
        }
        const float* tn = target + (long)(l0 + 1) * (D * DM);
        #pragma unroll
        for (int it = 0; it < 16; ++it)
            pf[it] = reinterpret_cast<const float4*>(tn)[it * 512 + t];
        const u16* qb = qk + (long)l0 * (H * DM) + hm * DM + w * 128 + g * 8;
        #pragma unroll
        for (int ks = 0; ks < 4; ++ks)
            qc[0][ks] = *reinterpret_cast<const bf16x8*>(&qb[ks * 32]);
    }
    __syncthreads();

    #pragma unroll
    for (int li = 0; li < NLV5; ++li) {
        const int l = l0 + li;
        const int cur = li & 1, nxt = cur ^ 1;
        u16* curS = cur ? tgtS1 : tgtS0;
        u16* nxtS = cur ? tgtS0 : tgtS1;

        const float* mrow = mask + (long)l * D;
        float mk[8];
        #pragma unroll
        for (int r = 0; r < 4; ++r) { mk[r] = mrow[4 * g + r]; mk[4 + r] = mrow[16 + 4 * g + r]; }

        if (li < NLV5 - 1) {
            #pragma unroll
            for (int it = 0; it < 16; ++it) {
                const int i = it * 512 + t;
                const int d = i >> 8, mm = (i & 255) * 4, cc = mm ^ ((d & 15) << 3);
                u16x4 o = { f2bf(pf[it].x), f2bf(pf[it].y), f2bf(pf[it].z), f2bf(pf[it].w) };
                *reinterpret_cast<u16x4*>(&nxtS[d * DM + cc]) = o;
            }
            if (li < NLV5 - 2) {
                const float* tn = target + (long)(l + 2) * (D * DM);
                #pragma unroll
                for (int it = 0; it < 16; ++it)
                    pf[it] = reinterpret_cast<const float4*>(tn)[it * 512 + t];
            }
            const u16* qn = qk + (long)(l + 1) * (H * DM) + hm * DM + w * 128 + g * 8;
            #pragma unroll
            for (int ks = 0; ks < 4; ++ks)
                qc[nxt][ks] = *reinterpret_cast<const bf16x8*>(&qn[ks * 32]);
        }

        // ---- QK: partial scores over this wave's 128-k slice (proven map) ----
        f32x4 a0 = {0.f, 0.f, 0.f, 0.f}, a1 = {0.f, 0.f, 0.f, 0.f};
        const int swz = hm << 3;
        #pragma unroll
        for (int ks = 0; ks < 4; ++ks) {
            const int mcol = w * 128 + ks * 32 + g * 8;
            const bf16x8 x0 = *reinterpret_cast<const bf16x8*>(&curS[hm * DM + (mcol ^ swz)]);
            const bf16x8 x1 = *reinterpret_cast<const bf16x8*>(&curS[(16 + hm) * DM + (mcol ^ swz)]);
            a0 = __builtin_amdgcn_mfma_f32_16x16x32_bf16(x0, qc[cur][ks], a0, 0, 0, 0);
            a1 = __builtin_amdgcn_mfma_f32_16x16x32_bf16(x1, qc[cur][ks], a1, 0, 0, 0);
        }
        red[(w * 2 + 0) * 64 + lane] = a0;
        red[(w * 2 + 1) * 64 + lane] = a1;
        __syncthreads();

        f32x4 s0 = red[lane], s1 = red[64 + lane];
        #pragma unroll
        for (int ww = 1; ww < 8; ++ww) {
            s0 += red[(ww * 2 + 0) * 64 + lane];
            s1 += red[(ww * 2 + 1) * 64 + lane];
        }

        // ---- softmax over d (lane holds d = {4g+r, 16+4g+r} for h = hm) ----
        float sc[8];
        #pragma unroll
        for (int r = 0; r < 4; ++r) {
            sc[r]     = s0[r] * 0.125f + mk[r];
            sc[4 + r] = s1[r] * 0.125f + mk[4 + r];
        }
        float mx = sc[0];
        #pragma unroll
        for (int r = 1; r < 8; ++r) mx = fmaxf(mx, sc[r]);
        mx = fmaxf(mx, __shfl_xor(mx, 16));
        mx = fmaxf(mx, __shfl_xor(mx, 32));
        float sum = 0.f;
        #pragma unroll
        for (int r = 0; r < 8; ++r) { sc[r] = __expf(sc[r] - mx); sum += sc[r]; }
        sum += __shfl_xor(sum, 16);
        sum += __shfl_xor(sum, 32);
        const float pinv = 1.0f / sum;
        bf16x8 pfrag;
        #pragma unroll
        for (int r = 0; r < 8; ++r) pfrag[r] = (short)f2bf(sc[r] * pinv);

        // ---- PV: 8 m-tiles per wave; A = tgt^T via scalar LDS reads, B = P ----
        u16* twl = tw + (long)l * (H * DM);
        const f32x4 zero = {0.f, 0.f, 0.f, 0.f};
        #pragma unroll
        for (int i = 0; i < 8; ++i) {
            const int mg = w * 8 + i;
            const int m = mg * 16 + hm;
            bf16x8 af;
            #pragma unroll
            for (int j = 0; j < 4; ++j) {
                const int d0 = 4 * g + j;
                const int d1 = 16 + 4 * g + j;
                af[j]     = (short)curS[d0 * DM + (m ^ (d0 << 3))];
                af[4 + j] = (short)curS[d1 * DM + (m ^ (d0 << 3))];
            }
            const f32x4 c = __builtin_amdgcn_mfma_f32_16x16x32_bf16(af, pfrag, zero, 0, 0, 0);
            u16x4 o = { f2bf(c[0]), f2bf(c[1]), f2bf(c[2]), f2bf(c[3]) };
            *reinterpret_cast<u16x4*>(&twl[hm * DM + mg * 16 + 4 * g]) = o;
        }
        __syncthreads();   // all reads of curS/red done -> next iter may overwrite
    }
}

// ---------------- fused residual-add + LayerNorm ----------------
// out = LN(a + sum_{zi<nz} Z[zi] + bvec) * g + be. Z partials stacked at zstride.
__global__ __launch_bounds__(256) void ln_fuse(
    const float* __restrict__ a, const float* __restrict__ zb, int nz, long zstride,
    const float* __restrict__ bvec,
    const float* __restrict__ g, const float* __restrict__ be,
    float* __restrict__ o32, u16* __restrict__ o16)
{
    const int l = blockIdx.x, t = threadIdx.x;
    __shared__ float S[4], SS[4];
    __shared__ float stats[2];
    const float4 va = reinterpret_cast<const float4*>(a + (long)l * DM)[t];
    float v[4] = { va.x, va.y, va.z, va.w };
    for (int zi = 0; zi < nz; ++zi) {
        const float4 q = reinterpret_cast<const float4*>(zb + (long)zi * zstride + (long)l * DM)[t];
        v[0] += q.x; v[1] += q.y; v[2] += q.z; v[3] += q.w;
    }
    if (bvec) {
        const float4 vv = reinterpret_cast<const float4*>(bvec)[t];
        v[0] += vv.x; v[1] += vv.y; v[2] += vv.z; v[3] += vv.w;
    }
    float s  = v[0] + v[1] + v[2] + v[3];
    float ss = v[0]*v[0] + v[1]*v[1] + v[2]*v[2] + v[3]*v[3];
    #pragma unroll
    for (int off = 32; off; off >>= 1) { s += __shfl_down(s, off); ss += __shfl_down(ss, off); }
    if ((t & 63) == 0) { S[t >> 6] = s; SS[t >> 6] = ss; }
    __syncthreads();
    if (t == 0) {
        const float St  = S[0] + S[1] + S[2] + S[3];
        const float SSt = SS[0] + SS[1] + SS[2] + SS[3];
        const float mu  = St * (1.f / DM);
        const float var = fmaxf(SSt * (1.f / DM) - mu * mu, 0.f);
        stats[0] = mu;
        stats[1] = rsqrtf(var + 1e-5f);
    }
    __syncthreads();
    const float mu = stats[0], rs = stats[1];
    const int c0 = t * 4;
    float ov[4];
    #pragma unroll
    for (int j = 0; j < 4; ++j) ov[j] = (v[j] - mu) * rs * g[c0 + j] + be[c0 + j];
    float4 o; o.x = ov[0]; o.y = ov[1]; o.z = ov[2]; o.w = ov[3];
    reinterpret_cast<float4*>(o32 + (long)l * DM)[t] = o;
    if (o16) {
        u16x4 q = { f2bf(ov[0]), f2bf(ov[1]), f2bf(ov[2]), f2bf(ov[3]) };
        *reinterpret_cast<u16x4*>(o16 + (long)l * DM + c0) = q;
    }
}

// ---------------- launcher ----------------
extern "C" void kernel_launch(void* const* d_in, const int* in_sizes, int n_in,
                              void* d_out, int out_size, void* d_ws, size_t ws_size,
                              hipStream_t stream)
{
    const float* src    = (const float*)d_in[0];
    const float* target = (const float*)d_in[1];
    const float* amask  = (const float*)d_in[2];
    const float* Wq = (const float*)d_in[3];
    const float* bq = (const float*)d_in[4];
    const float* Wk = (const float*)d_in[5];
    const float* Wv = (const float*)d_in[7];
    const float* bv = (const float*)d_in[8];
    const float* W1 = (const float*)d_in[9];
    const float* b1 = (const float*)d_in[10];
    const float* W2 = (const float*)d_in[11];
    const float* b2 = (const float*)d_in[12];
    const float* g1  = (const float*)d_in[13];
    const float* be1 = (const float*)d_in[14];
    const float* g2  = (const float*)d_in[15];
    const float* be2 = (const float*)d_in[16];

    // Workspace arena (peak 158 MB). qk region (30..94) dead after attn; tw region
    // (94..158) dead after G3 -> G5's 4 split-K partials go there.
    char* ws = (char*)d_ws;
    const size_t MB = (size_t)1 << 20;
    u16*   src16 = (u16*)  (ws +  0 * MB);  //  4 MB  bf16(src)
    u16*   Wk16  = (u16*)  (ws +  4 * MB);  //  2 MB  bf16(Wk)
    u16*   WqT   = (u16*)  (ws +  6 * MB);  //  2 MB  bf16(Wq^T)
    u16*   WvT   = (u16*)  (ws +  8 * MB);  //  2 MB  bf16(Wv^T)
    u16*   W1T   = (u16*)  (ws + 10 * MB);  //  8 MB  bf16(W1^T)
    u16*   W2T   = (u16*)  (ws + 18 * MB);  //  8 MB  bf16(W2^T)
    u16*   Q16   = (u16*)  (ws + 26 * MB);  //  4 MB  q = src@Wq+bq
    u16*   qk16  = (u16*)  (ws + 30 * MB);  // 64 MB  qk[l,h,m]
    u16*   Y16   = (u16*)  (ws + 30 * MB);  // 16 MB  gelu(x@W1+b1)   [aliases dead qk]
    float* ctx32 = (float*)(ws + 54 * MB);  //  8 MB  attention ctx   [dead after LN1]
    float* x32   = (float*)(ws + 62 * MB);  //  8 MB  LN1 out         [live till LN2]
    u16*   x16   = (u16*)  (ws + 70 * MB);  //  4 MB  bf16(x)
    u16*   tw16  = (u16*)  (ws + 94 * MB);  // 64 MB  tw              [dead after G3]
    float* Z32   = (float*)(ws + 94 * MB);  // 32 MB  Y@W2 4 split-K partials [aliases dead tw]

    // conversions (2 fused launches)
    prep_bf<<<3072, 256, 0, stream>>>(src, src16, Wk, Wk16);
    prep_T<<<10240, dim3(32, 8), 0, stream>>>(Wq, WqT, Wv, WvT, W1, W1T, W2, W2T);

    // G1: Q = bf16(src @ Wq + bq)   [BN=64 -> 256 blocks = 1/CU]
    gemm128<0, 64><<<dim3(DM / 64, L / 128, 1), 256, 0, stream>>>(
        src16, DM, 0, WqT, DM, 0, Q16, DM, 0, bq, 0, DM);
    // G2 (batched over heads): qk[l,h,c] = sum_t Q[l,h,t] * Wk[c, h*64+t]   (K=64)
    gemm128<0, 128><<<dim3(DM / 128, L / 128, H), 256, 0, stream>>>(
        Q16, DM, DH, Wk16, DM, DH, qk16, H * DM, DM, nullptr, 0, DH);

    // fused MFMA attention (144 KB dynamic LDS double-buffer pipeline)
    (void)hipFuncSetAttribute(reinterpret_cast<const void*>(&attn_v5),
                              hipFuncAttributeMaxDynamicSharedMemorySize, 144 * 1024);
    attn_v5<<<L / NLV5, 512, 144 * 1024, stream>>>(qk16, target, amask, tw16);

    // G3 (batched over heads): ctx[l, h*64+j] = sum_m tw[l,h,m] * Wv[m, h*64+j] + bv
    gemm128<1, 64><<<dim3(1, L / 128, H), 256, 0, stream>>>(
        tw16, H * DM, DM, WvT, DM, (long)DH * DM, ctx32, DM, DH, bv, DH, DM);
    // x = LN(src + ctx)
    ln_fuse<<<L, 256, 0, stream>>>(src, ctx32, 1, 0, nullptr, g1, be1, x32, x16);
    // G4: Y = bf16(gelu(x @ W1 + b1))   [128x128 tile, 512 blocks]
    gemm128<2, 128><<<dim3(FF / 128, L / 128, 1), 256, 0, stream>>>(
        x16, DM, 0, W1T, DM, 0, Y16, FF, 0, b1, 0, DM);
    // G5: Z = Y @ W2 (f32), split-K z=4 -> 1024 blocks = 4/CU; partials in dead tw region
    gemm128<1, 128><<<dim3(DM / 128, L / 128, 4), 256, 0, stream>>>(
        Y16, FF, 1024, W2T, FF, 1024, Z32, DM, (long)L * DM, nullptr, 0, 1024);
    // out = LN(x + Z0 + Z1 + Z2 + Z3 + b2)
    ln_fuse<<<L, 256, 0, stream>>>(x32, Z32, 4, (long)L * DM, b2, g2, be2, (float*)d_out, nullptr);
}

// Round 12
// 242.415 us; speedup vs baseline: 1.2537x; 1.0346x over previous
//
#include <hip/hip_runtime.h>
#include <hip/hip_bf16.h>

// Problem constants
#define L  2048
#define D  32
#define DM 1024
#define H  16
#define DH 64
#define FF 4096

typedef unsigned short u16;
typedef __attribute__((ext_vector_type(8))) short bf16x8;   // MFMA A/B operand (8 bf16)
typedef __attribute__((ext_vector_type(4))) float f32x4;    // MFMA C/D operand
typedef __attribute__((ext_vector_type(4))) unsigned int u32x4;
typedef __attribute__((ext_vector_type(8))) unsigned short u16x8;
typedef __attribute__((ext_vector_type(4))) unsigned short u16x4;

static __device__ __forceinline__ u16 f2bf(float f) {
    union { __hip_bfloat16 b; u16 u; } cv;
    cv.b = __float2bfloat16(f);
    return cv.u;
}
// async global->LDS, 16B per lane. LDS dest must be wave-uniform base + lane*16
// (our r*64+sg*8 pattern == base + lane*8 elems, verified linear).
static __device__ __forceinline__ void gll16(const u16* gsrc, u16* ldst) {
    __builtin_amdgcn_global_load_lds(
        (const __attribute__((address_space(1))) unsigned int*)gsrc,
        (__attribute__((address_space(3))) unsigned int*)ldst, 16, 0, 0);
}

// ---------------- single fused conversion kernel ----------------
// blocks [0,10240): transpose+cvt of Wq/Wv/W1/W2 (32x32 tiles, (32,8) logical)
// blocks [10240,13312): linear bf16 cvt of src (2048 blocks) and Wk (1024 blocks)
__global__ __launch_bounds__(256) void prep_all(
    const float* __restrict__ src, u16* __restrict__ osrc,
    const float* __restrict__ Wk,  u16* __restrict__ oWk,
    const float* __restrict__ Wq,  u16* __restrict__ oWq,
    const float* __restrict__ Wv,  u16* __restrict__ oWv,
    const float* __restrict__ W1,  u16* __restrict__ oW1,
    const float* __restrict__ W2,  u16* __restrict__ oW2)
{
    const int b = blockIdx.x, t = threadIdx.x;
    if (b >= 10240) {
        const int i = (b - 10240) * 256 + t;
        const int na4 = (L * DM) / 4;
        const float* in;  u16* out;  int j;
        if (i < na4) { in = src; out = osrc; j = i; }
        else         { in = Wk;  out = oWk;  j = i - na4; }
        const float4 v = reinterpret_cast<const float4*>(in)[j];
        u16x4 o = { f2bf(v.x), f2bf(v.y), f2bf(v.z), f2bf(v.w) };
        *reinterpret_cast<u16x4*>(out + (long)j * 4) = o;
        return;
    }
    __shared__ float tile[32][33];
    const float* in; u16* out; int R, C, bx, by;
    if (b < 1024)      { in = Wq; out = oWq; R = DM; C = DM; int bb = b;        bx = (bb & 31) * 32;  by = (bb >> 5) * 32; }
    else if (b < 2048) { in = Wv; out = oWv; R = DM; C = DM; int bb = b - 1024; bx = (bb & 31) * 32;  by = (bb >> 5) * 32; }
    else if (b < 6144) { in = W1; out = oW1; R = DM; C = FF; int bb = b - 2048; bx = (bb & 127) * 32; by = (bb >> 7) * 32; }
    else               { in = W2; out = oW2; R = FF; C = DM; int bb = b - 6144; bx = (bb & 31) * 32;  by = (bb >> 5) * 32; }
    const int tx = t & 31, ty = t >> 5;
    #pragma unroll
    for (int i = 0; i < 32; i += 8)
        tile[ty + i][tx] = in[(long)(by + ty + i) * C + bx + tx];
    __syncthreads();
    #pragma unroll
    for (int i = 0; i < 32; i += 8)
        out[(long)(bx + ty + i) * R + by + tx] = f2bf(tile[tx][ty + i]);
}

// ---------------- 128xBN-tile MFMA GEMM, optional 2-phase LDS double-buffer ----------------
// 256 threads = 4 waves in 2x2; per-wave 64 x BN/2 (acc[4][BN/32]). BK=64.
// Staging via global_load_lds width=16, linear LDS dest; bank conflicts broken by the
// two-sided granule XOR swizzle (proven r7-r11). XCD-aware bijective block swizzle.
// PIPE=1 (T3-minimum 2-phase): prologue-stage tile0; per tile {stage t+1 into buf^1;
//   ds_read+MFMA from buf; __syncthreads (drains vmcnt+lgkm, barrier); swap}.
//   Race-audit: stage writes buf^1 only, reads hit buf only; barrier covers all waves'
//   loads before swap; next iter overwrites old buf only after all reads done. Correct.
// PIPE=0 (for K=64, e.g. G2): single buffer, stage->sync->compute (pipelining vacuous,
//   and smaller LDS keeps more blocks/CU for latency hiding).
// EPI: 0 = bf16 store, 1 = f32 store, 2 = exact gelu -> bf16 store.
template<int EPI, int BN, int PIPE>
__global__ __launch_bounds__(256) void gemm128(
    const u16* __restrict__ A, int lda, long aZ,
    const u16* __restrict__ Bt, int ldb, long bZ,
    void* __restrict__ Cv, int ldc, long cZ,
    const float* __restrict__ bias, int biasZ, int K)
{
    constexpr int NI = BN / 32;          // B-frags per wave / stage iters
    constexpr int ASZ = 128 * 64, BSZ = BN * 64;
    __shared__ u16 As[(PIPE ? 2 : 1) * ASZ];
    __shared__ u16 Bs[(PIPE ? 2 : 1) * BSZ];
    const int t = threadIdx.x, lane = t & 63, w = t >> 6;
    const int z = blockIdx.z;
    // XCD swizzle (bijective: all grids here have nxy % 8 == 0)
    const int nxy = gridDim.x * gridDim.y;
    int fid = blockIdx.y * gridDim.x + blockIdx.x;
    const int q8 = nxy >> 3;
    fid = (fid & 7) * q8 + (fid >> 3);
    const int bx = fid % gridDim.x, by = fid / gridDim.x;
    const int mBase = by * 128, nBase = bx * BN;
    const u16* Ab = A + (long)z * aZ;
    const u16* Bb = Bt + (long)z * bZ;
    const int wr = w >> 1, wc = w & 1;
    const int sr = lane >> 3, sg = lane & 7, sswz = sg ^ sr;   // staging row-in-8 / granule
    f32x4 acc[4][NI];
    #pragma unroll
    for (int mi = 0; mi < 4; ++mi)
        #pragma unroll
        for (int ni = 0; ni < NI; ++ni) acc[mi][ni] = (f32x4){0.f, 0.f, 0.f, 0.f};

    // ---- staging helper (identical addressing to the r7-r11 proven kernel) ----
    auto STAGE = [&](int buf, int k0) {
        u16* Ad = As + buf * ASZ;
        u16* Bd = Bs + buf * BSZ;
        #pragma unroll
        for (int i = 0; i < 4; ++i) {
            const int r = w * 32 + i * 8 + sr;                 // r&7 == sr
            gll16(&Ab[(long)(mBase + r) * lda + k0 + sswz * 8], &Ad[r * 64 + sg * 8]);
        }
        #pragma unroll
        for (int i = 0; i < NI; ++i) {
            const int r = w * (BN / 4) + i * 8 + sr;
            gll16(&Bb[(long)(nBase + r) * ldb + k0 + sswz * 8], &Bd[r * 64 + sg * 8]);
        }
    };

    if (PIPE) { STAGE(0, 0); }
    int cur = 0;
    for (int k0 = 0; k0 < K; k0 += 64) {
        if (!PIPE) {
            STAGE(0, k0);
            __syncthreads();
        } else {
            __syncthreads();                    // buf[cur] ready (prev iter / prologue)
            if (k0 + 64 < K) STAGE(cur ^ 1, k0 + 64);   // overlap: stage next during compute
        }
        const u16* Ar = As + cur * ASZ;
        const u16* Br = Bs + cur * BSZ;
        __builtin_amdgcn_s_setprio(1);
        #pragma unroll
        for (int ks = 0; ks < 2; ++ks) {
            bf16x8 aF[4], bF[NI];
            #pragma unroll
            for (int mi = 0; mi < 4; ++mi) {
                const int rr = wr * 64 + mi * 16 + (lane & 15);
                aF[mi] = *reinterpret_cast<const bf16x8*>(
                    &Ar[rr * 64 + ((ks * 4 + (lane >> 4)) ^ (rr & 7)) * 8]);
            }
            #pragma unroll
            for (int ni = 0; ni < NI; ++ni) {
                const int rr = wc * (BN / 2) + ni * 16 + (lane & 15);
                bF[ni] = *reinterpret_cast<const bf16x8*>(
                    &Br[rr * 64 + ((ks * 4 + (lane >> 4)) ^ (rr & 7)) * 8]);
            }
            #pragma unroll
            for (int mi = 0; mi < 4; ++mi)
                #pragma unroll
                for (int ni = 0; ni < NI; ++ni)
                    acc[mi][ni] = __builtin_amdgcn_mfma_f32_16x16x32_bf16(
                        aF[mi], bF[ni], acc[mi][ni], 0, 0, 0);
        }
        __builtin_amdgcn_s_setprio(0);
        if (!PIPE) __syncthreads();             // reads done before next overwrite
        if (PIPE) cur ^= 1;
    }
    const int rb = mBase + wr * 64 + ((lane >> 4) << 2);
    const int cb = nBase + wc * (BN / 2) + (lane & 15);
    #pragma unroll
    for (int mi = 0; mi < 4; ++mi) {
        #pragma unroll
        for (int ni = 0; ni < NI; ++ni) {
            const int col = cb + ni * 16;
            const float badd = bias ? bias[(long)z * biasZ + col] : 0.f;
            #pragma unroll
            for (int i = 0; i < 4; ++i) {
                float v = acc[mi][ni][i] + badd;
                if (EPI == 2) v = 0.5f * v * (1.f + erff(v * 0.70710678118654752f));
                const long off = (long)z * cZ + (long)(rb + mi * 16 + i) * ldc + col;
                if (EPI == 1) reinterpret_cast<float*>(Cv)[off] = v;
                else          reinterpret_cast<u16*>(Cv)[off]  = f2bf(v);
            }
        }
    }
}

// ---------------- attention v5: LDS double-buffer pipeline (r10/r11 passing, unchanged) ----------------
#define NLV5 8
__global__ __launch_bounds__(512, 2) void attn_v5(
    const u16* __restrict__ qk,        // [L][H][DM] bf16
    const float* __restrict__ target,  // [L][D][DM] f32
    const float* __restrict__ mask,    // [L][D]     f32
    u16* __restrict__ tw)              // [L][H][DM] bf16
{
    extern __shared__ u16 smem[];
    u16*   tgtS0 = smem;                         // 32768 u16
    u16*   tgtS1 = smem + D * DM;                // 32768 u16
    f32x4* red   = (f32x4*)(smem + 2 * D * DM);  // 16 KB: [w*2+t][lane]

    const int t = threadIdx.x, lane = t & 63, w = t >> 6;
    const int g = lane >> 4, hm = lane & 15;
    const int l0 = blockIdx.x * NLV5;

    float4 pf[16];
    bf16x8 qc[2][4];   // double-buffered qk k-slices; [li&1] is current
    {
        const float* tl = target + (long)l0 * (D * DM);
        #pragma unroll
        for (int it = 0; it < 16; ++it)
            pf[it] = reinterpret_cast<const float4*>(tl)[it * 512 + t];
        #pragma unroll
        for (int it = 0; it < 16; ++it) {
            const int i = it * 512 + t;
            const int d = i >> 8, mm = (i & 255) * 4, cc = mm ^ ((d & 15) << 3);
            u16x4 o = { f2bf(pf[it].x), f2bf(pf[it].y), f2bf(pf[it].z), f2bf(pf[it].w) };
            *reinterpret_cast<u16x4*>(&tgtS0[d * DM + cc]) = o;
        }
        const float* tn = target + (long)(l0 + 1) * (D * DM);
        #pragma unroll
        for (int it = 0; it < 16; ++it)
            pf[it] = reinterpret_cast<const float4*>(tn)[it * 512 + t];
        const u16* qb = qk + (long)l0 * (H * DM) + hm * DM + w * 128 + g * 8;
        #pragma unroll
        for (int ks = 0; ks < 4; ++ks)
            qc[0][ks] = *reinterpret_cast<const bf16x8*>(&qb[ks * 32]);
    }
    __syncthreads();

    #pragma unroll
    for (int li = 0; li < NLV5; ++li) {
        const int l = l0 + li;
        const int cur = li & 1, nxt = cur ^ 1;
        u16* curS = cur ? tgtS1 : tgtS0;
        u16* nxtS = cur ? tgtS0 : tgtS1;

        const float* mrow = mask + (long)l * D;
        float mk[8];
        #pragma unroll
        for (int r = 0; r < 4; ++r) { mk[r] = mrow[4 * g + r]; mk[4 + r] = mrow[16 + 4 * g + r]; }

        if (li < NLV5 - 1) {
            #pragma unroll
            for (int it = 0; it < 16; ++it) {
                const int i = it * 512 + t;
                const int d = i >> 8, mm = (i & 255) * 4, cc = mm ^ ((d & 15) << 3);
                u16x4 o = { f2bf(pf[it].x), f2bf(pf[it].y), f2bf(pf[it].z), f2bf(pf[it].w) };
                *reinterpret_cast<u16x4*>(&nxtS[d * DM + cc]) = o;
            }
            if (li < NLV5 - 2) {
                const float* tn = target + (long)(l + 2) * (D * DM);
                #pragma unroll
                for (int it = 0; it < 16; ++it)
                    pf[it] = reinterpret_cast<const float4*>(tn)[it * 512 + t];
            }
            const u16* qn = qk + (long)(l + 1) * (H * DM) + hm * DM + w * 128 + g * 8;
            #pragma unroll
            for (int ks = 0; ks < 4; ++ks)
                qc[nxt][ks] = *reinterpret_cast<const bf16x8*>(&qn[ks * 32]);
        }

        // ---- QK: partial scores over this wave's 128-k slice (proven map) ----
        f32x4 a0 = {0.f, 0.f, 0.f, 0.f}, a1 = {0.f, 0.f, 0.f, 0.f};
        const int swz = hm << 3;
        #pragma unroll
        for (int ks = 0; ks < 4; ++ks) {
            const int mcol = w * 128 + ks * 32 + g * 8;
            const bf16x8 x0 = *reinterpret_cast<const bf16x8*>(&curS[hm * DM + (mcol ^ swz)]);
            const bf16x8 x1 = *reinterpret_cast<const bf16x8*>(&curS[(16 + hm) * DM + (mcol ^ swz)]);
            a0 = __builtin_amdgcn_mfma_f32_16x16x32_bf16(x0, qc[cur][ks], a0, 0, 0, 0);
            a1 = __builtin_amdgcn_mfma_f32_16x16x32_bf16(x1, qc[cur][ks], a1, 0, 0, 0);
        }
        red[(w * 2 + 0) * 64 + lane] = a0;
        red[(w * 2 + 1) * 64 + lane] = a1;
        __syncthreads();

        f32x4 s0 = red[lane], s1 = red[64 + lane];
        #pragma unroll
        for (int ww = 1; ww < 8; ++ww) {
            s0 += red[(ww * 2 + 0) * 64 + lane];
            s1 += red[(ww * 2 + 1) * 64 + lane];
        }

        // ---- softmax over d (lane holds d = {4g+r, 16+4g+r} for h = hm) ----
        float sc[8];
        #pragma unroll
        for (int r = 0; r < 4; ++r) {
            sc[r]     = s0[r] * 0.125f + mk[r];
            sc[4 + r] = s1[r] * 0.125f + mk[4 + r];
        }
        float mx = sc[0];
        #pragma unroll
        for (int r = 1; r < 8; ++r) mx = fmaxf(mx, sc[r]);
        mx = fmaxf(mx, __shfl_xor(mx, 16));
        mx = fmaxf(mx, __shfl_xor(mx, 32));
        float sum = 0.f;
        #pragma unroll
        for (int r = 0; r < 8; ++r) { sc[r] = __expf(sc[r] - mx); sum += sc[r]; }
        sum += __shfl_xor(sum, 16);
        sum += __shfl_xor(sum, 32);
        const float pinv = 1.0f / sum;
        bf16x8 pfrag;
        #pragma unroll
        for (int r = 0; r < 8; ++r) pfrag[r] = (short)f2bf(sc[r] * pinv);

        // ---- PV: 8 m-tiles per wave; A = tgt^T via scalar LDS reads, B = P ----
        u16* twl = tw + (long)l * (H * DM);
        const f32x4 zero = {0.f, 0.f, 0.f, 0.f};
        #pragma unroll
        for (int i = 0; i < 8; ++i) {
            const int mg = w * 8 + i;
            const int m = mg * 16 + hm;
            bf16x8 af;
            #pragma unroll
            for (int j = 0; j < 4; ++j) {
                const int d0 = 4 * g + j;
                const int d1 = 16 + 4 * g + j;
                af[j]     = (short)curS[d0 * DM + (m ^ (d0 << 3))];
                af[4 + j] = (short)curS[d1 * DM + (m ^ (d0 << 3))];
            }
            const f32x4 c = __builtin_amdgcn_mfma_f32_16x16x32_bf16(af, pfrag, zero, 0, 0, 0);
            u16x4 o = { f2bf(c[0]), f2bf(c[1]), f2bf(c[2]), f2bf(c[3]) };
            *reinterpret_cast<u16x4*>(&twl[hm * DM + mg * 16 + 4 * g]) = o;
        }
        __syncthreads();   // all reads of curS/red done -> next iter may overwrite
    }
}

// ---------------- fused residual-add + LayerNorm ----------------
// out = LN(a + sum_{zi<nz} Z[zi] + bvec) * g + be. Z partials stacked at zstride.
__global__ __launch_bounds__(256) void ln_fuse(
    const float* __restrict__ a, const float* __restrict__ zb, int nz, long zstride,
    const float* __restrict__ bvec,
    const float* __restrict__ g, const float* __restrict__ be,
    float* __restrict__ o32, u16* __restrict__ o16)
{
    const int l = blockIdx.x, t = threadIdx.x;
    __shared__ float S[4], SS[4];
    __shared__ float stats[2];
    const float4 va = reinterpret_cast<const float4*>(a + (long)l * DM)[t];
    float v[4] = { va.x, va.y, va.z, va.w };
    for (int zi = 0; zi < nz; ++zi) {
        const float4 q = reinterpret_cast<const float4*>(zb + (long)zi * zstride + (long)l * DM)[t];
        v[0] += q.x; v[1] += q.y; v[2] += q.z; v[3] += q.w;
    }
    if (bvec) {
        const float4 vv = reinterpret_cast<const float4*>(bvec)[t];
        v[0] += vv.x; v[1] += vv.y; v[2] += vv.z; v[3] += vv.w;
    }
    float s  = v[0] + v[1] + v[2] + v[3];
    float ss = v[0]*v[0] + v[1]*v[1] + v[2]*v[2] + v[3]*v[3];
    #pragma unroll
    for (int off = 32; off; off >>= 1) { s += __shfl_down(s, off); ss += __shfl_down(ss, off); }
    if ((t & 63) == 0) { S[t >> 6] = s; SS[t >> 6] = ss; }
    __syncthreads();
    if (t == 0) {
        const float St  = S[0] + S[1] + S[2] + S[3];
        const float SSt = SS[0] + SS[1] + SS[2] + SS[3];
        const float mu  = St * (1.f / DM);
        const float var = fmaxf(SSt * (1.f / DM) - mu * mu, 0.f);
        stats[0] = mu;
        stats[1] = rsqrtf(var + 1e-5f);
    }
    __syncthreads();
    const float mu = stats[0], rs = stats[1];
    const int c0 = t * 4;
    float ov[4];
    #pragma unroll
    for (int j = 0; j < 4; ++j) ov[j] = (v[j] - mu) * rs * g[c0 + j] + be[c0 + j];
    float4 o; o.x = ov[0]; o.y = ov[1]; o.z = ov[2]; o.w = ov[3];
    reinterpret_cast<float4*>(o32 + (long)l * DM)[t] = o;
    if (o16) {
        u16x4 q = { f2bf(ov[0]), f2bf(ov[1]), f2bf(ov[2]), f2bf(ov[3]) };
        *reinterpret_cast<u16x4*>(o16 + (long)l * DM + c0) = q;
    }
}

// ---------------- launcher ----------------
extern "C" void kernel_launch(void* const* d_in, const int* in_sizes, int n_in,
                              void* d_out, int out_size, void* d_ws, size_t ws_size,
                              hipStream_t stream)
{
    const float* src    = (const float*)d_in[0];
    const float* target = (const float*)d_in[1];
    const float* amask  = (const float*)d_in[2];
    const float* Wq = (const float*)d_in[3];
    const float* bq = (const float*)d_in[4];
    const float* Wk = (const float*)d_in[5];
    const float* Wv = (const float*)d_in[7];
    const float* bv = (const float*)d_in[8];
    const float* W1 = (const float*)d_in[9];
    const float* b1 = (const float*)d_in[10];
    const float* W2 = (const float*)d_in[11];
    const float* b2 = (const float*)d_in[12];
    const float* g1  = (const float*)d_in[13];
    const float* be1 = (const float*)d_in[14];
    const float* g2  = (const float*)d_in[15];
    const float* be2 = (const float*)d_in[16];

    // Workspace arena (peak 158 MB). qk region (30..94) dead after attn; tw region
    // (94..158) dead after G3 -> G5's 4 split-K partials go there.
    char* ws = (char*)d_ws;
    const size_t MB = (size_t)1 << 20;
    u16*   src16 = (u16*)  (ws +  0 * MB);  //  4 MB  bf16(src)
    u16*   Wk16  = (u16*)  (ws +  4 * MB);  //  2 MB  bf16(Wk)
    u16*   WqT   = (u16*)  (ws +  6 * MB);  //  2 MB  bf16(Wq^T)
    u16*   WvT   = (u16*)  (ws +  8 * MB);  //  2 MB  bf16(Wv^T)
    u16*   W1T   = (u16*)  (ws + 10 * MB);  //  8 MB  bf16(W1^T)
    u16*   W2T   = (u16*)  (ws + 18 * MB);  //  8 MB  bf16(W2^T)
    u16*   Q16   = (u16*)  (ws + 26 * MB);  //  4 MB  q = src@Wq+bq
    u16*   qk16  = (u16*)  (ws + 30 * MB);  // 64 MB  qk[l,h,m]
    u16*   Y16   = (u16*)  (ws + 30 * MB);  // 16 MB  gelu(x@W1+b1)   [aliases dead qk]
    float* ctx32 = (float*)(ws + 54 * MB);  //  8 MB  attention ctx   [dead after LN1]
    float* x32   = (float*)(ws + 62 * MB);  //  8 MB  LN1 out         [live till LN2]
    u16*   x16   = (u16*)  (ws + 70 * MB);  //  4 MB  bf16(x)
    u16*   tw16  = (u16*)  (ws + 94 * MB);  // 64 MB  tw              [dead after G3]
    float* Z32   = (float*)(ws + 94 * MB);  // 32 MB  Y@W2 4 split-K partials [aliases dead tw]

    // conversions (1 fused launch)
    prep_all<<<13312, 256, 0, stream>>>(src, src16, Wk, Wk16,
                                        Wq, WqT, Wv, WvT, W1, W1T, W2, W2T);

    // G1: Q = bf16(src @ Wq + bq)   [BN=64, 2-phase, 256 blocks]
    gemm128<0, 64, 1><<<dim3(DM / 64, L / 128, 1), 256, 0, stream>>>(
        src16, DM, 0, WqT, DM, 0, Q16, DM, 0, bq, 0, DM);
    // G2 (batched over heads): qk = Q @ Wk_h^T   (K=64 -> 1-phase, small LDS, 8/CU)
    gemm128<0, 128, 0><<<dim3(DM / 128, L / 128, H), 256, 0, stream>>>(
        Q16, DM, DH, Wk16, DM, DH, qk16, H * DM, DM, nullptr, 0, DH);

    // fused MFMA attention (144 KB dynamic LDS double-buffer pipeline)
    (void)hipFuncSetAttribute(reinterpret_cast<const void*>(&attn_v5),
                              hipFuncAttributeMaxDynamicSharedMemorySize, 144 * 1024);
    attn_v5<<<L / NLV5, 512, 144 * 1024, stream>>>(qk16, target, amask, tw16);

    // G3 (batched over heads): ctx = tw @ Wv_h + bv   [BN=64, 2-phase]
    gemm128<1, 64, 1><<<dim3(1, L / 128, H), 256, 0, stream>>>(
        tw16, H * DM, DM, WvT, DM, (long)DH * DM, ctx32, DM, DH, bv, DH, DM);
    // x = LN(src + ctx)
    ln_fuse<<<L, 256, 0, stream>>>(src, ctx32, 1, 0, nullptr, g1, be1, x32, x16);
    // G4: Y = bf16(gelu(x @ W1 + b1))   [BN=128, 2-phase, 512 blocks]
    gemm128<2, 128, 1><<<dim3(FF / 128, L / 128, 1), 256, 0, stream>>>(
        x16, DM, 0, W1T, DM, 0, Y16, FF, 0, b1, 0, DM);
    // G5: Z = Y @ W2 (f32), split-K z=4, 2-phase; partials in dead tw region
    gemm128<1, 128, 1><<<dim3(DM / 128, L / 128, 4), 256, 0, stream>>>(
        Y16, FF, 1024, W2T, FF, 1024, Z32, DM, (long)L * DM, nullptr, 0, 1024);
    // out = LN(x + Z0 + Z1 + Z2 + Z3 + b2)
    ln_fuse<<<L, 256, 0, stream>>>(x32, Z32, 4, (long)L * DM, b2, g2, be2, (float*)d_out, nullptr);
}